// Round 4
// baseline (731.684 us; speedup 1.0000x reference)
//
#include <hip/hip_runtime.h>
#include <hip/hip_bf16.h>
#include <type_traits>

#define S_TOK 8192
#define HID 1024
#define INTERX 4096
#define NEXP 8
#define CAPX 1024
#define MTOT 16384   // merged M: 8192 expert slots + 8192 tokens

using f32x4 = __attribute__((ext_vector_type(4))) float;
using bf16x8 = __attribute__((ext_vector_type(8))) short;

__device__ __forceinline__ short f2bf(float f) {
    union { float f; unsigned u; } v; v.f = f;
    unsigned r = (v.u + 0x7FFFu + ((v.u >> 16) & 1u)) >> 16;
    return (short)r;
}
__device__ __forceinline__ float bflo(int p) {
    union { unsigned u; float f; } v; v.u = (unsigned)p << 16; return v.f;
}
__device__ __forceinline__ float bfhi(int p) {
    union { unsigned u; float f; } v; v.u = (unsigned)p & 0xffff0000u; return v.f;
}

// gelu(x) = x / (1 + e^{-2u}), u = 0.79788456(x + 0.044715x^3)
__device__ __forceinline__ float gelu_f(float x) {
    float x2 = x * x;
    float t = __expf(x * fmaf(x2, -0.07135677f, -1.5957691f));
    return x * __builtin_amdgcn_rcpf(1.0f + t);
}

__device__ __forceinline__ void gl_lds16(const short* g, short* l) {
    __builtin_amdgcn_global_load_lds(
        (const __attribute__((address_space(1))) void*)g,
        (__attribute__((address_space(3))) void*)l, 16, 0, 0);
}

// ---------------------------------------------------------------------------
// Transpose-convert body, 9-way batch: z<8 -> src_e + z*sSrc, z==8 -> src_r.
// src [K][N] fp32 -> dst[z] [N][K] bf16. PERM: apply pi within 64-k groups,
// pi(kl) = (kl&15)*4 + (kl>>4)  (must match GEMM1's packed-store layout).
// ---------------------------------------------------------------------------
template<int PERM>
__device__ __forceinline__ void convtrans_body(
    short (*tile)[72],
    const float* __restrict__ src_e, const float* __restrict__ src_r,
    short* __restrict__ dst, int K, int N, long sSrc, long sDst,
    int bxi, int byi, long z)
{
    const float* s = (z < 8) ? (src_e + z * sSrc) : src_r;
    short* d = dst + z * sDst;
    int n0 = bxi * 64, k0 = byi * 64;
    int t = threadIdx.x;
    int br = t >> 4, bc = t & 15;
    const float* sp = s + (long)(k0 + br * 4) * N + n0 + bc * 4;
    float4 r0 = *(const float4*)(sp);
    float4 r1 = *(const float4*)(sp + N);
    float4 r2 = *(const float4*)(sp + 2 * (long)N);
    float4 r3 = *(const float4*)(sp + 3 * (long)N);
    if (PERM) {
        float rr[4][4] = { {r0.x,r0.y,r0.z,r0.w}, {r1.x,r1.y,r1.z,r1.w},
                           {r2.x,r2.y,r2.z,r2.w}, {r3.x,r3.y,r3.z,r3.w} };
#pragma unroll
        for (int j = 0; j < 4; j++) {
            int kl = br * 4 + j;
            int kp = (kl & 15) * 4 + (kl >> 4);
#pragma unroll
            for (int q = 0; q < 4; q++)
                tile[bc * 4 + q][kp] = f2bf(rr[j][q]);
        }
    } else {
        short4 c0 = { f2bf(r0.x), f2bf(r1.x), f2bf(r2.x), f2bf(r3.x) };
        short4 c1 = { f2bf(r0.y), f2bf(r1.y), f2bf(r2.y), f2bf(r3.y) };
        short4 c2 = { f2bf(r0.z), f2bf(r1.z), f2bf(r2.z), f2bf(r3.z) };
        short4 c3 = { f2bf(r0.w), f2bf(r1.w), f2bf(r2.w), f2bf(r3.w) };
        *(short4*)&tile[bc * 4 + 0][br * 4] = c0;
        *(short4*)&tile[bc * 4 + 1][br * 4] = c1;
        *(short4*)&tile[bc * 4 + 2][br * 4] = c2;
        *(short4*)&tile[bc * 4 + 3][br * 4] = c3;
    }
    __syncthreads();
    int n = t >> 2, kc = (t & 3) * 16;
    int4 o0 = *(const int4*)&tile[n][kc];
    int4 o1 = *(const int4*)&tile[n][kc + 8];
    short* dp = d + (long)(n0 + n) * K + k0 + kc;
    *(int4*)(dp) = o0;
    *(int4*)(dp + 8) = o1;
}

template<int PERM>
__global__ __launch_bounds__(256) void convtrans_kernel(
    const float* __restrict__ src_e, const float* __restrict__ src_r,
    short* __restrict__ dst, int K, int N, long sSrc, long sDst)
{
    __shared__ __align__(16) short tile[64][72];
    convtrans_body<PERM>(tile, src_e, src_r, dst, K, N, sSrc, sDst,
                         blockIdx.x, blockIdx.y, (long)blockIdx.z);
}

// ---------------------------------------------------------------------------
// Fused pre-pass: blockIdx.z < 9  -> convtrans<0> (weights for GEMM1)
//                 blockIdx.z >= 9 -> LayerNorm + gate logits + coef logits
// (independent work merged into one launch: overlaps the two memory streams
//  and removes one launch gap). Grid dim3(64, 16, 17), 256 threads.
// ---------------------------------------------------------------------------
__global__ __launch_bounds__(256) void fused_pre_kernel(
    const float* __restrict__ src_e, const float* __restrict__ src_r,
    short* __restrict__ w1t,
    const float* __restrict__ x, const float* __restrict__ nw, const float* __restrict__ nb,
    const float* __restrict__ wg, const float* __restrict__ rcf,
    short* __restrict__ attn_bf, int* __restrict__ eidx, float* __restrict__ gate,
    float* __restrict__ coef0, float* __restrict__ coef1,
    int* __restrict__ map2, int* __restrict__ zbufi)
{
    __shared__ __align__(16) short tile[64][72];   // 18 KiB, aliased by LN branch
    int z = blockIdx.z;
    if (z < 9) {
        convtrans_body<0>(tile, src_e, src_r, w1t, HID, INTERX,
                          (long)HID * INTERX, (long)HID * INTERX,
                          blockIdx.x, blockIdx.y, (long)z);
        return;
    }
    // ---- LayerNorm + gate branch ----
    int s = (z - 9) * 1024 + blockIdx.y * 64 + blockIdx.x;   // 0..8191
    int tid = threadIdx.x;
    int lane = tid & 63, wave = tid >> 6;
    double (*gred)[10] = (double(*)[10])(&tile[0][0]);       // 320 B
    float  (*wred)[2]  = (float(*)[2])(&tile[32][0]);        // offset 4608 B

    if (tid == 0) {
        map2[s] = -1;                 // expert-slot region default
        map2[NEXP * CAPX + s] = s;    // residual region identity
    }
    if (s == 0) ((int2*)zbufi)[tid] = int2{0, 0};

    float4 xv = *(const float4*)(x + (size_t)s * HID + tid * 4);
    float sum = xv.x + xv.y + xv.z + xv.w;
    float sq  = xv.x*xv.x + xv.y*xv.y + xv.z*xv.z + xv.w*xv.w;
#pragma unroll
    for (int o = 32; o > 0; o >>= 1) {
        sum += __shfl_down(sum, o, 64);
        sq  += __shfl_down(sq, o, 64);
    }
    if (lane == 0) { wred[wave][0] = sum; wred[wave][1] = sq; }
    __syncthreads();
    float ts = wred[0][0] + wred[1][0] + wred[2][0] + wred[3][0];
    float tq = wred[0][1] + wred[1][1] + wred[2][1] + wred[3][1];
    float m  = ts * (1.0f / HID);
    float var = tq * (1.0f / HID) - m * m;
    float rs = rsqrtf(var + 1e-12f);

    float4 g4 = *(const float4*)(nw + tid * 4);
    float4 b4 = *(const float4*)(nb + tid * 4);
    float y[4];
    y[0] = (xv.x - m) * rs * g4.x + b4.x;
    y[1] = (xv.y - m) * rs * g4.y + b4.y;
    y[2] = (xv.z - m) * rs * g4.z + b4.z;
    y[3] = (xv.w - m) * rs * g4.w + b4.w;

    short4 yb = { f2bf(y[0]), f2bf(y[1]), f2bf(y[2]), f2bf(y[3]) };
    *(short4*)(attn_bf + (size_t)s * HID + tid * 4) = yb;

    double a[10];
#pragma unroll
    for (int q = 0; q < 10; q++) a[q] = 0.0;
#pragma unroll
    for (int j = 0; j < 4; j++) {
        int k = tid * 4 + j;
        float4 w0 = *(const float4*)(wg + k * 8);
        float4 w1 = *(const float4*)(wg + k * 8 + 4);
        double yj = (double)y[j];
        a[0] += yj * w0.x; a[1] += yj * w0.y; a[2] += yj * w0.z; a[3] += yj * w0.w;
        a[4] += yj * w1.x; a[5] += yj * w1.y; a[6] += yj * w1.z; a[7] += yj * w1.w;
        float2 rc = *(const float2*)(rcf + k * 2);
        a[8] += yj * rc.x; a[9] += yj * rc.y;
    }
#pragma unroll
    for (int o = 32; o > 0; o >>= 1)
#pragma unroll
        for (int q = 0; q < 10; q++) a[q] += __shfl_down(a[q], o, 64);
    if (lane == 0)
#pragma unroll
        for (int q = 0; q < 10; q++) gred[wave][q] = a[q];
    __syncthreads();
    if (tid == 0) {
        float l[8];
#pragma unroll
        for (int e = 0; e < 8; e++)
            l[e] = (float)(gred[0][e] + gred[1][e] + gred[2][e] + gred[3][e]);
        int bi = 0; float bv = l[0];
#pragma unroll
        for (int e = 1; e < 8; e++) if (l[e] > bv) { bv = l[e]; bi = e; }
        float den = 0.0f;
#pragma unroll
        for (int e = 0; e < 8; e++) den += expf(l[e] - bv);
        gate[s] = 1.0f / den;
        eidx[s] = bi;
        float r0 = (float)(gred[0][8] + gred[1][8] + gred[2][8] + gred[3][8]);
        float r1 = (float)(gred[0][9] + gred[1][9] + gred[2][9] + gred[3][9]);
        float mx = fmaxf(r0, r1);
        float e0 = expf(r0 - mx), e1 = expf(r1 - mx);
        float inv = 1.0f / (e0 + e1);
        coef0[s] = e0 * inv; coef1[s] = e1 * inv;
    }
}

// ---------------------------------------------------------------------------
// Capacity assignment (token-order exclusive cumsum per expert), 1 block.
// eidx staged coalesced into LDS first (old version did 2x uncoalesced
// stride-128B global reads with zero TLP to hide latency).
// ---------------------------------------------------------------------------
__global__ __launch_bounds__(256) void assign_kernel(
    const int* __restrict__ eidx, int* __restrict__ slot, int* __restrict__ map2)
{
    int tid = threadIdx.x;
    __shared__ int se[S_TOK];          // 32 KiB
    __shared__ int cnt[2][256][NEXP];  // 16 KiB
#pragma unroll
    for (int i = 0; i < S_TOK / 4 / 256; i++)      // 8 coalesced int4 loads
        ((int4*)se)[tid + i * 256] = ((const int4*)eidx)[tid + i * 256];
    __syncthreads();

    int c[NEXP];
#pragma unroll
    for (int e = 0; e < NEXP; e++) c[e] = 0;
    int base = tid * 32;
#pragma unroll
    for (int q = 0; q < 8; q++) {
        int4 v = ((const int4*)se)[tid * 8 + q];
        c[v.x]++; c[v.y]++; c[v.z]++; c[v.w]++;
    }
#pragma unroll
    for (int e = 0; e < NEXP; e++) cnt[0][tid][e] = c[e];
    __syncthreads();

    int src = 0;
    for (int step = 1; step < 256; step <<= 1) {
        int dst = src ^ 1;
#pragma unroll
        for (int e = 0; e < NEXP; e++) {
            int v = cnt[src][tid][e];
            if (tid >= step) v += cnt[src][tid - step][e];
            cnt[dst][tid][e] = v;
        }
        __syncthreads();
        src = dst;
    }
    int off[NEXP];
#pragma unroll
    for (int e = 0; e < NEXP; e++) off[e] = (tid > 0) ? cnt[src][tid - 1][e] : 0;
    for (int t = 0; t < 32; t++) {
        int s = base + t;
        int e = se[s];
        int loc = off[e]++;
        if (loc < CAPX) { slot[s] = loc; map2[e * CAPX + loc] = s; }
        else            { slot[s] = -1; }
    }
}

// ---------------------------------------------------------------------------
// Merged GEMM, 128(M)x256(N) block, 4 waves of 64x128, BK=64.  (round-0,
// harness-verified) global_load_lds staging + XOR chunk swizzle
// (conflict-free b128 frag reads).
// EPI 1: gelu + pi-packed int2 bf16 stores (k-dim permuted within 64-groups,
//        matched by convtrans<1> on the next GEMM's weights).
// EPI 0: bias + scalar bf16 stores, plain layout.
// ---------------------------------------------------------------------------
template<int EPI, int GATHER>
__global__ __launch_bounds__(256, 2) void gemm_kernel(
    const short* __restrict__ A, const short* __restrict__ W,
    const float* __restrict__ bias_e, const float* __restrict__ bias_r,
    short* __restrict__ out, const int* __restrict__ map2,
    const short* __restrict__ zbuf, int N, int K, long sW, long sB)
{
    __shared__ __align__(16) short a_lds[128 * 64];
    __shared__ __align__(16) short b_lds[256 * 64];

    // swizzle: 16 consecutive by-panels per XCD (L%8), bx outer within XCD
    int L = blockIdx.x + gridDim.x * blockIdx.y;
    int by = (L & 7) * 16 + ((L >> 3) & 15);
    int bx = L >> 7;

    long e = by >> 3; if (e > 8) e = 8;
    const short* Wb = W + e * sW;
    const float* biasb = (by < 64) ? (bias_e + e * sB) : bias_r;

    int tid = threadIdx.x;
    int lane = tid & 63, wave = tid >> 6;
    int wm = wave & 1, wn = wave >> 1;
    int lm = lane & 15, lq = lane >> 4;
    int lr = lane >> 3, ch = lane & 7;
    int chs = (ch ^ lr) * 8;               // XOR-swizzled global chunk offset

    const short* pA[4];
    const short* pB[8];
#pragma unroll
    for (int it = 0; it < 4; it++) {
        int row = (wave * 4 + it) * 8 + lr;            // 0..127
        if (GATHER) {
            int s = map2[by * 128 + row];
            pA[it] = (s >= 0) ? (A + (long)s * K) : zbuf;
        } else {
            pA[it] = A + ((long)by * 128 + row) * K;
        }
    }
#pragma unroll
    for (int it = 0; it < 8; it++) {
        int row = (wave * 8 + it) * 8 + lr;            // 0..255
        pB[it] = Wb + ((long)bx * 256 + row) * K;
    }

    f32x4 acc[4][8];
#pragma unroll
    for (int i = 0; i < 4; i++)
#pragma unroll
        for (int j = 0; j < 8; j++) acc[i][j] = { 0.f, 0.f, 0.f, 0.f };

    for (int kb = 0; kb < K; kb += 64) {
#pragma unroll
        for (int it = 0; it < 4; it++)
            gl_lds16(pA[it] + kb + chs, a_lds + (wave * 4 + it) * 512);
#pragma unroll
        for (int it = 0; it < 8; it++)
            gl_lds16(pB[it] + kb + chs, b_lds + (wave * 8 + it) * 512);
        __syncthreads();
#pragma unroll
        for (int ks = 0; ks < 64; ks += 32) {
            int po = ((lq ^ (lm & 7)) * 8) ^ ks;
            bf16x8 af[4], bfr[8];
#pragma unroll
            for (int i = 0; i < 4; i++)
                af[i] = *(const bf16x8*)(a_lds + (wm * 64 + i * 16 + lm) * 64 + po);
#pragma unroll
            for (int j = 0; j < 8; j++)
                bfr[j] = *(const bf16x8*)(b_lds + (wn * 128 + j * 16 + lm) * 64 + po);
#pragma unroll
            for (int i = 0; i < 4; i++)
#pragma unroll
                for (int j = 0; j < 8; j++)
                    acc[i][j] = __builtin_amdgcn_mfma_f32_16x16x32_bf16(af[i], bfr[j], acc[i][j], 0, 0, 0);
        }
        __syncthreads();
    }

    // epilogue: C/D layout col=lane&15 (lm), row=lq*4+r
    float bb[8];
#pragma unroll
    for (int j = 0; j < 8; j++)
        bb[j] = biasb[bx * 256 + wn * 128 + j * 16 + lm];

#pragma unroll
    for (int i = 0; i < 4; i++) {
#pragma unroll
        for (int r = 0; r < 4; r++) {
            long row = (long)by * 128 + wm * 64 + i * 16 + lq * 4 + r;
            if (EPI == 1) {
                short* rp = out + row * N + bx * 256 + wn * 128;
#pragma unroll
                for (int h = 0; h < 2; h++) {
                    int b0 = f2bf(gelu_f(acc[i][h*4+0][r] + bb[h*4+0]));
                    int b1 = f2bf(gelu_f(acc[i][h*4+1][r] + bb[h*4+1]));
                    int b2 = f2bf(gelu_f(acc[i][h*4+2][r] + bb[h*4+2]));
                    int b3 = f2bf(gelu_f(acc[i][h*4+3][r] + bb[h*4+3]));
                    int2 pk;
                    pk.x = (b0 & 0xFFFF) | (b1 << 16);
                    pk.y = (b2 & 0xFFFF) | (b3 << 16);
                    *(int2*)(rp + h * 64 + lm * 4) = pk;   // pi(c)=(c&15)*4+(c>>4)
                }
            } else {
#pragma unroll
                for (int j = 0; j < 8; j++) {
                    int col = bx * 256 + wn * 128 + j * 16 + lm;
                    out[row * N + col] = f2bf(acc[i][j][r] + bb[j]);
                }
            }
        }
    }
}

// ---------------------------------------------------------------------------
// Final combine: out = res_mlp*c0 + gate*expert_out*c1 + residual  (eout bf16)
// ---------------------------------------------------------------------------
__global__ __launch_bounds__(256) void final_kernel(
    const float* __restrict__ x, const short* __restrict__ eout2,
    const int* __restrict__ eidx, const int* __restrict__ slot,
    const float* __restrict__ gate, const float* __restrict__ coef0,
    const float* __restrict__ coef1, float* __restrict__ out)
{
    int s = blockIdx.x, tid = threadIdx.x;
    float c0 = coef0[s], g = gate[s] * coef1[s];
    int sl = slot[s], e = eidx[s];
    float4 xv = *(const float4*)(x + (size_t)s * HID + tid * 4);
    int2 rm = *(const int2*)(eout2 + ((size_t)(NEXP * CAPX + s)) * HID + tid * 4);
    int2 mo = { 0, 0 };
    if (sl >= 0) mo = *(const int2*)(eout2 + ((size_t)(e * CAPX + sl)) * HID + tid * 4);
    float4 o;
    o.x = bflo(rm.x) * c0 + g * bflo(mo.x) + xv.x;
    o.y = bfhi(rm.x) * c0 + g * bfhi(mo.x) + xv.y;
    o.z = bflo(rm.y) * c0 + g * bflo(mo.y) + xv.z;
    o.w = bfhi(rm.y) * c0 + g * bfhi(mo.y) + xv.w;
    *(float4*)(out + (size_t)s * HID + tid * 4) = o;
}

extern "C" void kernel_launch(void* const* d_in, const int* in_sizes, int n_in,
                              void* d_out, int out_size, void* d_ws, size_t ws_size,
                              hipStream_t stream) {
    const float* x           = (const float*)d_in[0];
    const float* attn_nw     = (const float*)d_in[1];
    const float* attn_nb     = (const float*)d_in[2];
    const float* wg          = (const float*)d_in[3];
    const float* inter_w     = (const float*)d_in[4];
    const float* inter_b     = (const float*)d_in[5];
    const float* output_w    = (const float*)d_in[6];
    const float* output_b    = (const float*)d_in[7];
    const float* res_inter_w = (const float*)d_in[8];
    const float* res_inter_b = (const float*)d_in[9];
    const float* res_output_w= (const float*)d_in[10];
    const float* res_output_b= (const float*)d_in[11];
    const float* res_coef    = (const float*)d_in[12];
    float* out = (float*)d_out;

    char* ws = (char*)d_ws;
    size_t off = 0;
    auto alloc = [&](size_t bytes) { void* p = ws + off; off += (bytes + 255) & ~(size_t)255; return p; };
    // region1: attn_bf (16 MiB, dies after GEMM1) then eout2 (32 MiB, GEMM2 out)
    char* region1 = (char*)alloc((size_t)MTOT * HID * 2);               // 32 MiB
    // wreg: w1t [9][4096][1024] (dies after GEMM1) then w2t [9][1024][4096]
    short* wreg   = (short*)alloc((size_t)9 * HID * INTERX * 2);        // 72 MiB
    short* hbuf2  = (short*)alloc((size_t)MTOT * INTERX * 2);           // 128 MiB
    int*   eidx   = (int*)alloc(S_TOK * 4);
    int*   slot   = (int*)alloc(S_TOK * 4);
    float* gate   = (float*)alloc(S_TOK * 4);
    float* c0     = (float*)alloc(S_TOK * 4);
    float* c1     = (float*)alloc(S_TOK * 4);
    int*   map2   = (int*)alloc(MTOT * 4);
    short* zbuf   = (short*)alloc(1024 * 2);

    short* attn_bf = (short*)region1;
    short* eout2   = (short*)region1;
    short* w1t = wreg;
    short* w2t = wreg;

    // fused: weights for GEMM1 (z<9) + layernorm/gate (z>=9)
    fused_pre_kernel<<<dim3(64, 16, 17), 256, 0, stream>>>(
        inter_w, res_inter_w, w1t,
        x, attn_nw, attn_nb, wg, res_coef,
        attn_bf, eidx, gate, c0, c1, map2, (int*)zbuf);

    assign_kernel<<<1, 256, 0, stream>>>(eidx, slot, map2);

    // merged GEMM1: [16384,1024]@[9-sel][1024->4096] -> gelu -> hbuf2 (pi-packed)
    gemm_kernel<1, 1><<<dim3(INTERX/256, 128), 256, 0, stream>>>(
        attn_bf, w1t, inter_b, res_inter_b, hbuf2, map2, zbuf,
        INTERX, HID, (long)HID*INTERX, INTERX);

    // weights for GEMM2: [9][N=1024][K=4096] bf16, pi-permuted K (matches hbuf2)
    convtrans_kernel<1><<<dim3(HID/64, INTERX/64, 9), 256, 0, stream>>>(
        output_w, res_output_w, w2t, INTERX, HID, (long)INTERX*HID, (long)INTERX*HID);

    // merged GEMM2: [16384,4096]@[9-sel][4096->1024] -> eout2 bf16 (plain layout)
    gemm_kernel<0, 0><<<dim3(HID/256, 128), 256, 0, stream>>>(
        hbuf2, w2t, output_b, res_output_b, eout2, nullptr, zbuf,
        HID, INTERX, (long)INTERX*HID, HID);

    final_kernel<<<S_TOK, 256, 0, stream>>>(x, eout2, eidx, slot, gate, c0, c1, out);

    (void)in_sizes; (void)n_in; (void)out_size; (void)ws_size;
}

// Round 5
// 714.438 us; speedup vs baseline: 1.0241x; 1.0241x over previous
//
#include <hip/hip_runtime.h>
#include <hip/hip_bf16.h>
#include <type_traits>

#define S_TOK 8192
#define HID 1024
#define INTERX 4096
#define NEXP 8
#define CAPX 1024
#define MTOT 16384   // merged M: 8192 expert slots + 8192 tokens

using f32x4 = __attribute__((ext_vector_type(4))) float;
using bf16x8 = __attribute__((ext_vector_type(8))) short;

__device__ __forceinline__ short f2bf(float f) {
    union { float f; unsigned u; } v; v.f = f;
    unsigned r = (v.u + 0x7FFFu + ((v.u >> 16) & 1u)) >> 16;
    return (short)r;
}
__device__ __forceinline__ float bflo(int p) {
    union { unsigned u; float f; } v; v.u = (unsigned)p << 16; return v.f;
}
__device__ __forceinline__ float bfhi(int p) {
    union { unsigned u; float f; } v; v.u = (unsigned)p & 0xffff0000u; return v.f;
}

// gelu(x) = x / (1 + e^{-2u}), u = 0.79788456(x + 0.044715x^3)
__device__ __forceinline__ float gelu_f(float x) {
    float x2 = x * x;
    float t = __expf(x * fmaf(x2, -0.07135677f, -1.5957691f));
    return x * __builtin_amdgcn_rcpf(1.0f + t);
}

__device__ __forceinline__ void gl_lds16(const short* g, short* l) {
    __builtin_amdgcn_global_load_lds(
        (const __attribute__((address_space(1))) void*)g,
        (__attribute__((address_space(3))) void*)l, 16, 0, 0);
}

// ---------------------------------------------------------------------------
// Transpose-convert body, 9-way batch: z<8 -> src_e + z*sSrc, z==8 -> src_r.
// src [K][N] fp32 -> dst[z] [N][K] bf16. PERM: apply pi within 64-k groups,
// pi(kl) = (kl&15)*4 + (kl>>4)  (must match GEMM1's packed-store layout).
// ---------------------------------------------------------------------------
template<int PERM>
__device__ __forceinline__ void convtrans_body(
    short (*tile)[72],
    const float* __restrict__ src_e, const float* __restrict__ src_r,
    short* __restrict__ dst, int K, int N, long sSrc, long sDst,
    int bxi, int byi, long z)
{
    const float* s = (z < 8) ? (src_e + z * sSrc) : src_r;
    short* d = dst + z * sDst;
    int n0 = bxi * 64, k0 = byi * 64;
    int t = threadIdx.x;
    int br = t >> 4, bc = t & 15;
    const float* sp = s + (long)(k0 + br * 4) * N + n0 + bc * 4;
    float4 r0 = *(const float4*)(sp);
    float4 r1 = *(const float4*)(sp + N);
    float4 r2 = *(const float4*)(sp + 2 * (long)N);
    float4 r3 = *(const float4*)(sp + 3 * (long)N);
    if (PERM) {
        float rr[4][4] = { {r0.x,r0.y,r0.z,r0.w}, {r1.x,r1.y,r1.z,r1.w},
                           {r2.x,r2.y,r2.z,r2.w}, {r3.x,r3.y,r3.z,r3.w} };
#pragma unroll
        for (int j = 0; j < 4; j++) {
            int kl = br * 4 + j;
            int kp = (kl & 15) * 4 + (kl >> 4);
#pragma unroll
            for (int q = 0; q < 4; q++)
                tile[bc * 4 + q][kp] = f2bf(rr[j][q]);
        }
    } else {
        short4 c0 = { f2bf(r0.x), f2bf(r1.x), f2bf(r2.x), f2bf(r3.x) };
        short4 c1 = { f2bf(r0.y), f2bf(r1.y), f2bf(r2.y), f2bf(r3.y) };
        short4 c2 = { f2bf(r0.z), f2bf(r1.z), f2bf(r2.z), f2bf(r3.z) };
        short4 c3 = { f2bf(r0.w), f2bf(r1.w), f2bf(r2.w), f2bf(r3.w) };
        *(short4*)&tile[bc * 4 + 0][br * 4] = c0;
        *(short4*)&tile[bc * 4 + 1][br * 4] = c1;
        *(short4*)&tile[bc * 4 + 2][br * 4] = c2;
        *(short4*)&tile[bc * 4 + 3][br * 4] = c3;
    }
    __syncthreads();
    int n = t >> 2, kc = (t & 3) * 16;
    int4 o0 = *(const int4*)&tile[n][kc];
    int4 o1 = *(const int4*)&tile[n][kc + 8];
    short* dp = d + (long)(n0 + n) * K + k0 + kc;
    *(int4*)(dp) = o0;
    *(int4*)(dp + 8) = o1;
}

template<int PERM>
__global__ __launch_bounds__(256) void convtrans_kernel(
    const float* __restrict__ src_e, const float* __restrict__ src_r,
    short* __restrict__ dst, int K, int N, long sSrc, long sDst)
{
    __shared__ __align__(16) short tile[64][72];
    convtrans_body<PERM>(tile, src_e, src_r, dst, K, N, sSrc, sDst,
                         blockIdx.x, blockIdx.y, (long)blockIdx.z);
}

// ---------------------------------------------------------------------------
// Fused pre-pass: blockIdx.z < 9  -> convtrans<0> (weights for GEMM1)
//                 blockIdx.z >= 9 -> LayerNorm + gate logits + coef logits
// Grid dim3(64, 16, 17), 256 threads.
// ---------------------------------------------------------------------------
__global__ __launch_bounds__(256) void fused_pre_kernel(
    const float* __restrict__ src_e, const float* __restrict__ src_r,
    short* __restrict__ w1t,
    const float* __restrict__ x, const float* __restrict__ nw, const float* __restrict__ nb,
    const float* __restrict__ wg, const float* __restrict__ rcf,
    short* __restrict__ attn_bf, int* __restrict__ eidx, float* __restrict__ gate,
    float* __restrict__ coef0, float* __restrict__ coef1,
    int* __restrict__ map2, int* __restrict__ zbufi)
{
    __shared__ __align__(16) short tile[64][72];   // 9 KiB, aliased by LN branch
    int z = blockIdx.z;
    if (z < 9) {
        convtrans_body<0>(tile, src_e, src_r, w1t, HID, INTERX,
                          (long)HID * INTERX, (long)HID * INTERX,
                          blockIdx.x, blockIdx.y, (long)z);
        return;
    }
    // ---- LayerNorm + gate branch ----
    int s = (z - 9) * 1024 + blockIdx.y * 64 + blockIdx.x;   // 0..8191
    int tid = threadIdx.x;
    int lane = tid & 63, wave = tid >> 6;
    double (*gred)[10] = (double(*)[10])(&tile[0][0]);       // 320 B
    float  (*wred)[2]  = (float(*)[2])(&tile[32][0]);        // offset 4608 B

    if (tid == 0) {
        map2[s] = -1;                 // expert-slot region default
        map2[NEXP * CAPX + s] = s;    // residual region identity
    }
    if (s == 0) ((int2*)zbufi)[tid] = int2{0, 0};

    float4 xv = *(const float4*)(x + (size_t)s * HID + tid * 4);
    float sum = xv.x + xv.y + xv.z + xv.w;
    float sq  = xv.x*xv.x + xv.y*xv.y + xv.z*xv.z + xv.w*xv.w;
#pragma unroll
    for (int o = 32; o > 0; o >>= 1) {
        sum += __shfl_down(sum, o, 64);
        sq  += __shfl_down(sq, o, 64);
    }
    if (lane == 0) { wred[wave][0] = sum; wred[wave][1] = sq; }
    __syncthreads();
    float ts = wred[0][0] + wred[1][0] + wred[2][0] + wred[3][0];
    float tq = wred[0][1] + wred[1][1] + wred[2][1] + wred[3][1];
    float m  = ts * (1.0f / HID);
    float var = tq * (1.0f / HID) - m * m;
    float rs = rsqrtf(var + 1e-12f);

    float4 g4 = *(const float4*)(nw + tid * 4);
    float4 b4 = *(const float4*)(nb + tid * 4);
    float y[4];
    y[0] = (xv.x - m) * rs * g4.x + b4.x;
    y[1] = (xv.y - m) * rs * g4.y + b4.y;
    y[2] = (xv.z - m) * rs * g4.z + b4.z;
    y[3] = (xv.w - m) * rs * g4.w + b4.w;

    short4 yb = { f2bf(y[0]), f2bf(y[1]), f2bf(y[2]), f2bf(y[3]) };
    *(short4*)(attn_bf + (size_t)s * HID + tid * 4) = yb;

    double a[10];
#pragma unroll
    for (int q = 0; q < 10; q++) a[q] = 0.0;
#pragma unroll
    for (int j = 0; j < 4; j++) {
        int k = tid * 4 + j;
        float4 w0 = *(const float4*)(wg + k * 8);
        float4 w1 = *(const float4*)(wg + k * 8 + 4);
        double yj = (double)y[j];
        a[0] += yj * w0.x; a[1] += yj * w0.y; a[2] += yj * w0.z; a[3] += yj * w0.w;
        a[4] += yj * w1.x; a[5] += yj * w1.y; a[6] += yj * w1.z; a[7] += yj * w1.w;
        float2 rc = *(const float2*)(rcf + k * 2);
        a[8] += yj * rc.x; a[9] += yj * rc.y;
    }
#pragma unroll
    for (int o = 32; o > 0; o >>= 1)
#pragma unroll
        for (int q = 0; q < 10; q++) a[q] += __shfl_down(a[q], o, 64);
    if (lane == 0)
#pragma unroll
        for (int q = 0; q < 10; q++) gred[wave][q] = a[q];
    __syncthreads();
    if (tid == 0) {
        float l[8];
#pragma unroll
        for (int e = 0; e < 8; e++)
            l[e] = (float)(gred[0][e] + gred[1][e] + gred[2][e] + gred[3][e]);
        int bi = 0; float bv = l[0];
#pragma unroll
        for (int e = 1; e < 8; e++) if (l[e] > bv) { bv = l[e]; bi = e; }
        float den = 0.0f;
#pragma unroll
        for (int e = 0; e < 8; e++) den += expf(l[e] - bv);
        gate[s] = 1.0f / den;
        eidx[s] = bi;
        float r0 = (float)(gred[0][8] + gred[1][8] + gred[2][8] + gred[3][8]);
        float r1 = (float)(gred[0][9] + gred[1][9] + gred[2][9] + gred[3][9]);
        float mx = fmaxf(r0, r1);
        float e0 = expf(r0 - mx), e1 = expf(r1 - mx);
        float inv = 1.0f / (e0 + e1);
        coef0[s] = e0 * inv; coef1[s] = e1 * inv;
    }
}

// ---------------------------------------------------------------------------
// Capacity assignment (token-order exclusive cumsum per expert), 1 block.
// eidx staged coalesced into LDS first.
// ---------------------------------------------------------------------------
__global__ __launch_bounds__(256) void assign_kernel(
    const int* __restrict__ eidx, int* __restrict__ slot, int* __restrict__ map2)
{
    int tid = threadIdx.x;
    __shared__ int se[S_TOK];          // 32 KiB
    __shared__ int cnt[2][256][NEXP];  // 16 KiB
#pragma unroll
    for (int i = 0; i < S_TOK / 4 / 256; i++)      // 8 coalesced int4 loads
        ((int4*)se)[tid + i * 256] = ((const int4*)eidx)[tid + i * 256];
    __syncthreads();

    int c[NEXP];
#pragma unroll
    for (int e = 0; e < NEXP; e++) c[e] = 0;
    int base = tid * 32;
#pragma unroll
    for (int q = 0; q < 8; q++) {
        int4 v = ((const int4*)se)[tid * 8 + q];
        c[v.x]++; c[v.y]++; c[v.z]++; c[v.w]++;
    }
#pragma unroll
    for (int e = 0; e < NEXP; e++) cnt[0][tid][e] = c[e];
    __syncthreads();

    int src = 0;
    for (int step = 1; step < 256; step <<= 1) {
        int dst = src ^ 1;
#pragma unroll
        for (int e = 0; e < NEXP; e++) {
            int v = cnt[src][tid][e];
            if (tid >= step) v += cnt[src][tid - step][e];
            cnt[dst][tid][e] = v;
        }
        __syncthreads();
        src = dst;
    }
    int off[NEXP];
#pragma unroll
    for (int e = 0; e < NEXP; e++) off[e] = (tid > 0) ? cnt[src][tid - 1][e] : 0;
    for (int t = 0; t < 32; t++) {
        int s = base + t;
        int e = se[s];
        int loc = off[e]++;
        if (loc < CAPX) { slot[s] = loc; map2[e * CAPX + loc] = s; }
        else            { slot[s] = -1; }
    }
}

// ---------------------------------------------------------------------------
// Merged GEMM, 128(M)x256(N) block, 4 waves of 64x128, BK=64 (round-0,
// harness-verified structure). global_load_lds staging + XOR chunk swizzle.
// NEW: blocks with bid >= nGemm run convtrans<1> (weights for GEMM2) instead,
// so the 226 MB BW-bound transpose overlaps the compute-bound GEMM1
// (GEMM1 uses only ~18% of HBM). Requires w2t not aliasing w1t (checked by
// caller against ws_size; falls back to serial launch otherwise).
// EPI 1: gelu + pi-packed int2 bf16 stores. EPI 0: bias + bf16, plain.
// ---------------------------------------------------------------------------
template<int EPI, int GATHER>
__global__ __launch_bounds__(256, 2) void gemm_kernel(
    const short* __restrict__ A, const short* __restrict__ W,
    const float* __restrict__ bias_e, const float* __restrict__ bias_r,
    short* __restrict__ out, const int* __restrict__ map2,
    const short* __restrict__ zbuf, int N, int K, long sW, long sB,
    const float* __restrict__ cw_e, const float* __restrict__ cw_r,
    short* __restrict__ cdst, int nGemm)
{
    __shared__ __align__(16) short a_lds[128 * 64];
    __shared__ __align__(16) short b_lds[256 * 64];

    int bid = blockIdx.x + gridDim.x * blockIdx.y;
    if (bid >= nGemm) {
        // piggy-backed convtrans<1>: [K=4096][N=1024] fp32 -> [9][1024][4096] bf16
        int cid = bid - nGemm;      // 0..9215
        convtrans_body<1>((short(*)[72])a_lds, cw_e, cw_r, cdst,
                          INTERX, HID, (long)INTERX * HID, (long)INTERX * HID,
                          cid & 15, (cid >> 4) & 63, (long)(cid >> 10));
        return;
    }

    // swizzle: 16 consecutive by-panels per XCD (L%8), bx outer within XCD
    int L = bid;
    int by = (L & 7) * 16 + ((L >> 3) & 15);
    int bx = L >> 7;

    long e = by >> 3; if (e > 8) e = 8;
    const short* Wb = W + e * sW;
    const float* biasb = (by < 64) ? (bias_e + e * sB) : bias_r;

    int tid = threadIdx.x;
    int lane = tid & 63, wave = tid >> 6;
    int wm = wave & 1, wn = wave >> 1;
    int lm = lane & 15, lq = lane >> 4;
    int lr = lane >> 3, ch = lane & 7;
    int chs = (ch ^ lr) * 8;               // XOR-swizzled global chunk offset

    const short* pA[4];
    const short* pB[8];
#pragma unroll
    for (int it = 0; it < 4; it++) {
        int row = (wave * 4 + it) * 8 + lr;            // 0..127
        if (GATHER) {
            int s = map2[by * 128 + row];
            pA[it] = (s >= 0) ? (A + (long)s * K) : zbuf;
        } else {
            pA[it] = A + ((long)by * 128 + row) * K;
        }
    }
#pragma unroll
    for (int it = 0; it < 8; it++) {
        int row = (wave * 8 + it) * 8 + lr;            // 0..255
        pB[it] = Wb + ((long)bx * 256 + row) * K;
    }

    f32x4 acc[4][8];
#pragma unroll
    for (int i = 0; i < 4; i++)
#pragma unroll
        for (int j = 0; j < 8; j++) acc[i][j] = { 0.f, 0.f, 0.f, 0.f };

    for (int kb = 0; kb < K; kb += 64) {
#pragma unroll
        for (int it = 0; it < 4; it++)
            gl_lds16(pA[it] + kb + chs, a_lds + (wave * 4 + it) * 512);
#pragma unroll
        for (int it = 0; it < 8; it++)
            gl_lds16(pB[it] + kb + chs, b_lds + (wave * 8 + it) * 512);
        __syncthreads();
#pragma unroll
        for (int ks = 0; ks < 64; ks += 32) {
            int po = ((lq ^ (lm & 7)) * 8) ^ ks;
            bf16x8 af[4], bfr[8];
#pragma unroll
            for (int i = 0; i < 4; i++)
                af[i] = *(const bf16x8*)(a_lds + (wm * 64 + i * 16 + lm) * 64 + po);
#pragma unroll
            for (int j = 0; j < 8; j++)
                bfr[j] = *(const bf16x8*)(b_lds + (wn * 128 + j * 16 + lm) * 64 + po);
#pragma unroll
            for (int i = 0; i < 4; i++)
#pragma unroll
                for (int j = 0; j < 8; j++)
                    acc[i][j] = __builtin_amdgcn_mfma_f32_16x16x32_bf16(af[i], bfr[j], acc[i][j], 0, 0, 0);
        }
        __syncthreads();
    }

    // epilogue: C/D layout col=lane&15 (lm), row=lq*4+r
    float bb[8];
#pragma unroll
    for (int j = 0; j < 8; j++)
        bb[j] = biasb[bx * 256 + wn * 128 + j * 16 + lm];

#pragma unroll
    for (int i = 0; i < 4; i++) {
#pragma unroll
        for (int r = 0; r < 4; r++) {
            long row = (long)by * 128 + wm * 64 + i * 16 + lq * 4 + r;
            if (EPI == 1) {
                short* rp = out + row * N + bx * 256 + wn * 128;
#pragma unroll
                for (int h = 0; h < 2; h++) {
                    int b0 = f2bf(gelu_f(acc[i][h*4+0][r] + bb[h*4+0]));
                    int b1 = f2bf(gelu_f(acc[i][h*4+1][r] + bb[h*4+1]));
                    int b2 = f2bf(gelu_f(acc[i][h*4+2][r] + bb[h*4+2]));
                    int b3 = f2bf(gelu_f(acc[i][h*4+3][r] + bb[h*4+3]));
                    int2 pk;
                    pk.x = (b0 & 0xFFFF) | (b1 << 16);
                    pk.y = (b2 & 0xFFFF) | (b3 << 16);
                    *(int2*)(rp + h * 64 + lm * 4) = pk;   // pi(c)=(c&15)*4+(c>>4)
                }
            } else {
#pragma unroll
                for (int j = 0; j < 8; j++) {
                    int col = bx * 256 + wn * 128 + j * 16 + lm;
                    out[row * N + col] = f2bf(acc[i][j][r] + bb[j]);
                }
            }
        }
    }
}

// ---------------------------------------------------------------------------
// Final combine: out = res_mlp*c0 + gate*expert_out*c1 + residual  (eout bf16)
// ---------------------------------------------------------------------------
__global__ __launch_bounds__(256) void final_kernel(
    const float* __restrict__ x, const short* __restrict__ eout2,
    const int* __restrict__ eidx, const int* __restrict__ slot,
    const float* __restrict__ gate, const float* __restrict__ coef0,
    const float* __restrict__ coef1, float* __restrict__ out)
{
    int s = blockIdx.x, tid = threadIdx.x;
    float c0 = coef0[s], g = gate[s] * coef1[s];
    int sl = slot[s], e = eidx[s];
    float4 xv = *(const float4*)(x + (size_t)s * HID + tid * 4);
    int2 rm = *(const int2*)(eout2 + ((size_t)(NEXP * CAPX + s)) * HID + tid * 4);
    int2 mo = { 0, 0 };
    if (sl >= 0) mo = *(const int2*)(eout2 + ((size_t)(e * CAPX + sl)) * HID + tid * 4);
    float4 o;
    o.x = bflo(rm.x) * c0 + g * bflo(mo.x) + xv.x;
    o.y = bfhi(rm.x) * c0 + g * bfhi(mo.x) + xv.y;
    o.z = bflo(rm.y) * c0 + g * bflo(mo.y) + xv.z;
    o.w = bfhi(rm.y) * c0 + g * bfhi(mo.y) + xv.w;
    *(float4*)(out + (size_t)s * HID + tid * 4) = o;
}

extern "C" void kernel_launch(void* const* d_in, const int* in_sizes, int n_in,
                              void* d_out, int out_size, void* d_ws, size_t ws_size,
                              hipStream_t stream) {
    const float* x           = (const float*)d_in[0];
    const float* attn_nw     = (const float*)d_in[1];
    const float* attn_nb     = (const float*)d_in[2];
    const float* wg          = (const float*)d_in[3];
    const float* inter_w     = (const float*)d_in[4];
    const float* inter_b     = (const float*)d_in[5];
    const float* output_w    = (const float*)d_in[6];
    const float* output_b    = (const float*)d_in[7];
    const float* res_inter_w = (const float*)d_in[8];
    const float* res_inter_b = (const float*)d_in[9];
    const float* res_output_w= (const float*)d_in[10];
    const float* res_output_b= (const float*)d_in[11];
    const float* res_coef    = (const float*)d_in[12];
    float* out = (float*)d_out;

    char* ws = (char*)d_ws;
    size_t off = 0;
    auto alloc = [&](size_t bytes) { void* p = ws + off; off += (bytes + 255) & ~(size_t)255; return p; };
    // region1: attn_bf (16 MiB, dies after GEMM1) then eout2 (32 MiB, GEMM2 out)
    char* region1 = (char*)alloc((size_t)MTOT * HID * 2);               // 32 MiB
    // wreg: w1t [9][4096][1024] bf16 (GEMM1 weights)
    short* wreg   = (short*)alloc((size_t)9 * HID * INTERX * 2);        // 72 MiB
    short* hbuf2  = (short*)alloc((size_t)MTOT * INTERX * 2);           // 128 MiB
    int*   eidx   = (int*)alloc(S_TOK * 4);
    int*   slot   = (int*)alloc(S_TOK * 4);
    float* gate   = (float*)alloc(S_TOK * 4);
    float* c0     = (float*)alloc(S_TOK * 4);
    float* c1     = (float*)alloc(S_TOK * 4);
    int*   map2   = (int*)alloc(MTOT * 4);
    short* zbuf   = (short*)alloc(1024 * 2);

    // w2t: separate 72 MiB if the workspace allows -> convtrans<1> can overlap
    // GEMM1 (fused into its grid). Otherwise alias wreg (serial, round-4 path).
    size_t off_base = off;
    short* w2t_sep = (short*)alloc((size_t)9 * HID * INTERX * 2);       // +72 MiB
    bool sep = (off <= ws_size);
    short* w2t = sep ? w2t_sep : wreg;
    if (!sep) off = off_base;

    short* attn_bf = (short*)region1;
    short* eout2   = (short*)region1;
    short* w1t = wreg;

    // fused: weights for GEMM1 (z<9) + layernorm/gate (z>=9)
    fused_pre_kernel<<<dim3(64, 16, 17), 256, 0, stream>>>(
        inter_w, res_inter_w, w1t,
        x, attn_nw, attn_nb, wg, res_coef,
        attn_bf, eidx, gate, c0, c1, map2, (int*)zbuf);

    assign_kernel<<<1, 256, 0, stream>>>(eidx, slot, map2);

    const int NG1 = (MTOT / 128) * (INTERX / 256);   // 2048 GEMM1 blocks

    if (sep) {
        // merged GEMM1 + piggy-backed convtrans<1> (9216 extra blocks -> w2t)
        gemm_kernel<1, 1><<<dim3(NG1 + 9216), 256, 0, stream>>>(
            attn_bf, w1t, inter_b, res_inter_b, hbuf2, map2, zbuf,
            INTERX, HID, (long)HID*INTERX, INTERX,
            output_w, res_output_w, w2t, NG1);
    } else {
        gemm_kernel<1, 1><<<dim3(NG1), 256, 0, stream>>>(
            attn_bf, w1t, inter_b, res_inter_b, hbuf2, map2, zbuf,
            INTERX, HID, (long)HID*INTERX, INTERX,
            nullptr, nullptr, nullptr, NG1);
        // weights for GEMM2: [9][N=1024][K=4096] bf16, pi-permuted K
        convtrans_kernel<1><<<dim3(HID/64, INTERX/64, 9), 256, 0, stream>>>(
            output_w, res_output_w, w2t, INTERX, HID,
            (long)INTERX*HID, (long)INTERX*HID);
    }

    // merged GEMM2: [16384,4096]@[9-sel][4096->1024] -> eout2 bf16 (plain layout)
    const int NG2 = (MTOT / 128) * (HID / 256);      // 512 blocks
    gemm_kernel<0, 0><<<dim3(NG2), 256, 0, stream>>>(
        hbuf2, w2t, output_b, res_output_b, eout2, nullptr, zbuf,
        HID, INTERX, (long)INTERX*HID, HID,
        nullptr, nullptr, nullptr, NG2);

    final_kernel<<<S_TOK, 256, 0, stream>>>(x, eout2, eidx, slot, gate, c0, c1, out);

    (void)in_sizes; (void)n_in; (void)out_size;
}

// Round 6
// 707.054 us; speedup vs baseline: 1.0348x; 1.0104x over previous
//
#include <hip/hip_runtime.h>
#include <hip/hip_bf16.h>
#include <type_traits>

#define S_TOK 8192
#define HID 1024
#define INTERX 4096
#define NEXP 8
#define CAPX 1024
#define MTOT 16384   // merged M: 8192 expert slots + 8192 tokens

using f32x4 = __attribute__((ext_vector_type(4))) float;
using bf16x8 = __attribute__((ext_vector_type(8))) short;

__device__ __forceinline__ short f2bf(float f) {
    union { float f; unsigned u; } v; v.f = f;
    unsigned r = (v.u + 0x7FFFu + ((v.u >> 16) & 1u)) >> 16;
    return (short)r;
}
__device__ __forceinline__ float bflo(int p) {
    union { unsigned u; float f; } v; v.u = (unsigned)p << 16; return v.f;
}
__device__ __forceinline__ float bfhi(int p) {
    union { unsigned u; float f; } v; v.u = (unsigned)p & 0xffff0000u; return v.f;
}

// gelu(x) = x / (1 + e^{-2u}), u = 0.79788456(x + 0.044715x^3)
__device__ __forceinline__ float gelu_f(float x) {
    float x2 = x * x;
    float t = __expf(x * fmaf(x2, -0.07135677f, -1.5957691f));
    return x * __builtin_amdgcn_rcpf(1.0f + t);
}

__device__ __forceinline__ void gl_lds16(const short* g, short* l) {
    __builtin_amdgcn_global_load_lds(
        (const __attribute__((address_space(1))) void*)g,
        (__attribute__((address_space(3))) void*)l, 16, 0, 0);
}

// ---------------------------------------------------------------------------
// Transpose-convert body, 9-way batch: z<8 -> src_e + z*sSrc, z==8 -> src_r.
// src [K][N] fp32 -> dst[z] [N][K] bf16. PERM: apply pi within 64-k groups,
// pi(kl) = (kl&15)*4 + (kl>>4)  (must match GEMM1's packed-store layout).
// ---------------------------------------------------------------------------
template<int PERM>
__device__ __forceinline__ void convtrans_body(
    short (*tile)[72],
    const float* __restrict__ src_e, const float* __restrict__ src_r,
    short* __restrict__ dst, int K, int N, long sSrc, long sDst,
    int bxi, int byi, long z)
{
    const float* s = (z < 8) ? (src_e + z * sSrc) : src_r;
    short* d = dst + z * sDst;
    int n0 = bxi * 64, k0 = byi * 64;
    int t = threadIdx.x;
    int br = t >> 4, bc = t & 15;
    const float* sp = s + (long)(k0 + br * 4) * N + n0 + bc * 4;
    float4 r0 = *(const float4*)(sp);
    float4 r1 = *(const float4*)(sp + N);
    float4 r2 = *(const float4*)(sp + 2 * (long)N);
    float4 r3 = *(const float4*)(sp + 3 * (long)N);
    if (PERM) {
        float rr[4][4] = { {r0.x,r0.y,r0.z,r0.w}, {r1.x,r1.y,r1.z,r1.w},
                           {r2.x,r2.y,r2.z,r2.w}, {r3.x,r3.y,r3.z,r3.w} };
#pragma unroll
        for (int j = 0; j < 4; j++) {
            int kl = br * 4 + j;
            int kp = (kl & 15) * 4 + (kl >> 4);
#pragma unroll
            for (int q = 0; q < 4; q++)
                tile[bc * 4 + q][kp] = f2bf(rr[j][q]);
        }
    } else {
        short4 c0 = { f2bf(r0.x), f2bf(r1.x), f2bf(r2.x), f2bf(r3.x) };
        short4 c1 = { f2bf(r0.y), f2bf(r1.y), f2bf(r2.y), f2bf(r3.y) };
        short4 c2 = { f2bf(r0.z), f2bf(r1.z), f2bf(r2.z), f2bf(r3.z) };
        short4 c3 = { f2bf(r0.w), f2bf(r1.w), f2bf(r2.w), f2bf(r3.w) };
        *(short4*)&tile[bc * 4 + 0][br * 4] = c0;
        *(short4*)&tile[bc * 4 + 1][br * 4] = c1;
        *(short4*)&tile[bc * 4 + 2][br * 4] = c2;
        *(short4*)&tile[bc * 4 + 3][br * 4] = c3;
    }
    __syncthreads();
    int n = t >> 2, kc = (t & 3) * 16;
    int4 o0 = *(const int4*)&tile[n][kc];
    int4 o1 = *(const int4*)&tile[n][kc + 8];
    short* dp = d + (long)(n0 + n) * K + k0 + kc;
    *(int4*)(dp) = o0;
    *(int4*)(dp + 8) = o1;
}

template<int PERM>
__global__ __launch_bounds__(256) void convtrans_kernel(
    const float* __restrict__ src_e, const float* __restrict__ src_r,
    short* __restrict__ dst, int K, int N, long sSrc, long sDst)
{
    __shared__ __align__(16) short tile[64][72];
    convtrans_body<PERM>(tile, src_e, src_r, dst, K, N, sSrc, sDst,
                         blockIdx.x, blockIdx.y, (long)blockIdx.z);
}

// ---------------------------------------------------------------------------
// Fused pre-pass: blockIdx.z < 9  -> convtrans<0> (weights for GEMM1)
//                 blockIdx.z >= 9 -> LayerNorm + gate logits + coef logits
// Grid dim3(64, 16, 17), 256 threads.
// ---------------------------------------------------------------------------
__global__ __launch_bounds__(256) void fused_pre_kernel(
    const float* __restrict__ src_e, const float* __restrict__ src_r,
    short* __restrict__ w1t,
    const float* __restrict__ x, const float* __restrict__ nw, const float* __restrict__ nb,
    const float* __restrict__ wg, const float* __restrict__ rcf,
    short* __restrict__ attn_bf, int* __restrict__ eidx, float* __restrict__ gate,
    float* __restrict__ coef0, float* __restrict__ coef1,
    int* __restrict__ map2, int* __restrict__ zbufi)
{
    __shared__ __align__(16) short tile[64][72];   // 9 KiB, aliased by LN branch
    int z = blockIdx.z;
    if (z < 9) {
        convtrans_body<0>(tile, src_e, src_r, w1t, HID, INTERX,
                          (long)HID * INTERX, (long)HID * INTERX,
                          blockIdx.x, blockIdx.y, (long)z);
        return;
    }
    // ---- LayerNorm + gate branch ----
    int s = (z - 9) * 1024 + blockIdx.y * 64 + blockIdx.x;   // 0..8191
    int tid = threadIdx.x;
    int lane = tid & 63, wave = tid >> 6;
    double (*gred)[10] = (double(*)[10])(&tile[0][0]);       // 320 B
    float  (*wred)[2]  = (float(*)[2])(&tile[32][0]);        // offset 4608 B

    if (tid == 0) {
        map2[s] = -1;                 // expert-slot region default
        map2[NEXP * CAPX + s] = s;    // residual region identity
    }
    if (s == 0) ((int2*)zbufi)[tid] = int2{0, 0};

    float4 xv = *(const float4*)(x + (size_t)s * HID + tid * 4);
    float sum = xv.x + xv.y + xv.z + xv.w;
    float sq  = xv.x*xv.x + xv.y*xv.y + xv.z*xv.z + xv.w*xv.w;
#pragma unroll
    for (int o = 32; o > 0; o >>= 1) {
        sum += __shfl_down(sum, o, 64);
        sq  += __shfl_down(sq, o, 64);
    }
    if (lane == 0) { wred[wave][0] = sum; wred[wave][1] = sq; }
    __syncthreads();
    float ts = wred[0][0] + wred[1][0] + wred[2][0] + wred[3][0];
    float tq = wred[0][1] + wred[1][1] + wred[2][1] + wred[3][1];
    float m  = ts * (1.0f / HID);
    float var = tq * (1.0f / HID) - m * m;
    float rs = rsqrtf(var + 1e-12f);

    float4 g4 = *(const float4*)(nw + tid * 4);
    float4 b4 = *(const float4*)(nb + tid * 4);
    float y[4];
    y[0] = (xv.x - m) * rs * g4.x + b4.x;
    y[1] = (xv.y - m) * rs * g4.y + b4.y;
    y[2] = (xv.z - m) * rs * g4.z + b4.z;
    y[3] = (xv.w - m) * rs * g4.w + b4.w;

    short4 yb = { f2bf(y[0]), f2bf(y[1]), f2bf(y[2]), f2bf(y[3]) };
    *(short4*)(attn_bf + (size_t)s * HID + tid * 4) = yb;

    double a[10];
#pragma unroll
    for (int q = 0; q < 10; q++) a[q] = 0.0;
#pragma unroll
    for (int j = 0; j < 4; j++) {
        int k = tid * 4 + j;
        float4 w0 = *(const float4*)(wg + k * 8);
        float4 w1 = *(const float4*)(wg + k * 8 + 4);
        double yj = (double)y[j];
        a[0] += yj * w0.x; a[1] += yj * w0.y; a[2] += yj * w0.z; a[3] += yj * w0.w;
        a[4] += yj * w1.x; a[5] += yj * w1.y; a[6] += yj * w1.z; a[7] += yj * w1.w;
        float2 rc = *(const float2*)(rcf + k * 2);
        a[8] += yj * rc.x; a[9] += yj * rc.y;
    }
#pragma unroll
    for (int o = 32; o > 0; o >>= 1)
#pragma unroll
        for (int q = 0; q < 10; q++) a[q] += __shfl_down(a[q], o, 64);
    if (lane == 0)
#pragma unroll
        for (int q = 0; q < 10; q++) gred[wave][q] = a[q];
    __syncthreads();
    if (tid == 0) {
        float l[8];
#pragma unroll
        for (int e = 0; e < 8; e++)
            l[e] = (float)(gred[0][e] + gred[1][e] + gred[2][e] + gred[3][e]);
        int bi = 0; float bv = l[0];
#pragma unroll
        for (int e = 1; e < 8; e++) if (l[e] > bv) { bv = l[e]; bi = e; }
        float den = 0.0f;
#pragma unroll
        for (int e = 0; e < 8; e++) den += expf(l[e] - bv);
        gate[s] = 1.0f / den;
        eidx[s] = bi;
        float r0 = (float)(gred[0][8] + gred[1][8] + gred[2][8] + gred[3][8]);
        float r1 = (float)(gred[0][9] + gred[1][9] + gred[2][9] + gred[3][9]);
        float mx = fmaxf(r0, r1);
        float e0 = expf(r0 - mx), e1 = expf(r1 - mx);
        float inv = 1.0f / (e0 + e1);
        coef0[s] = e0 * inv; coef1[s] = e1 * inv;
    }
}

// ---------------------------------------------------------------------------
// Capacity assignment (token-order exclusive cumsum per expert), 1 block.
// eidx staged coalesced into LDS first.
// ---------------------------------------------------------------------------
__global__ __launch_bounds__(256) void assign_kernel(
    const int* __restrict__ eidx, int* __restrict__ slot, int* __restrict__ map2)
{
    int tid = threadIdx.x;
    __shared__ int se[S_TOK];          // 32 KiB
    __shared__ int cnt[2][256][NEXP];  // 16 KiB
#pragma unroll
    for (int i = 0; i < S_TOK / 4 / 256; i++)      // 8 coalesced int4 loads
        ((int4*)se)[tid + i * 256] = ((const int4*)eidx)[tid + i * 256];
    __syncthreads();

    int c[NEXP];
#pragma unroll
    for (int e = 0; e < NEXP; e++) c[e] = 0;
    int base = tid * 32;
#pragma unroll
    for (int q = 0; q < 8; q++) {
        int4 v = ((const int4*)se)[tid * 8 + q];
        c[v.x]++; c[v.y]++; c[v.z]++; c[v.w]++;
    }
#pragma unroll
    for (int e = 0; e < NEXP; e++) cnt[0][tid][e] = c[e];
    __syncthreads();

    int src = 0;
    for (int step = 1; step < 256; step <<= 1) {
        int dst = src ^ 1;
#pragma unroll
        for (int e = 0; e < NEXP; e++) {
            int v = cnt[src][tid][e];
            if (tid >= step) v += cnt[src][tid - step][e];
            cnt[dst][tid][e] = v;
        }
        __syncthreads();
        src = dst;
    }
    int off[NEXP];
#pragma unroll
    for (int e = 0; e < NEXP; e++) off[e] = (tid > 0) ? cnt[src][tid - 1][e] : 0;
    for (int t = 0; t < 32; t++) {
        int s = base + t;
        int e = se[s];
        int loc = off[e]++;
        if (loc < CAPX) { slot[s] = loc; map2[e * CAPX + loc] = s; }
        else            { slot[s] = -1; }
    }
}

// ---------------------------------------------------------------------------
// Merged GEMM1, 128(M)x256(N) block, 4 waves of 64x128, BK=64 (round-0,
// harness-verified structure). global_load_lds staging + XOR chunk swizzle.
// ILV=1: convtrans<1> blocks INTERLEAVED into the grid, period 44 =
//   8 GEMM + 36 conv (2048=256x8, 9216=256x36), so every CU carries conv
//   (pure BW) work alongside GEMM (MFMA) work for the whole dispatch --
//   round-5's append-at-tail variant only overlapped the dispatch tail.
//   bid%8 of a GEMM block = (4*chunk + pos)&7, so by-group (L&7) stays
//   pinned to a stable XCD pair (locality mostly retained).
// ILV=0: plain GEMM grid (fallback when workspace can't hold separate w2t).
// EPI 1: gelu + pi-packed int2 bf16 stores. EPI 0: bias + bf16, plain.
// ---------------------------------------------------------------------------
template<int EPI, int GATHER, int ILV>
__global__ __launch_bounds__(256, 2) void gemm_kernel(
    const short* __restrict__ A, const short* __restrict__ W,
    const float* __restrict__ bias_e, const float* __restrict__ bias_r,
    short* __restrict__ out, const int* __restrict__ map2,
    const short* __restrict__ zbuf, int N, int K, long sW, long sB,
    const float* __restrict__ cw_e, const float* __restrict__ cw_r,
    short* __restrict__ cdst)
{
    __shared__ __align__(16) short a_lds[128 * 64];
    __shared__ __align__(16) short b_lds[256 * 64];

    int bid;
    if (ILV) {
        int raw = blockIdx.x;
        int chunk = raw / 44, pos = raw - chunk * 44;
        if (pos >= 8) {
            // interleaved convtrans<1>: [4096][1024] fp32 -> [9][1024][4096] bf16
            int cid = chunk * 36 + (pos - 8);    // 0..9215
            convtrans_body<1>((short(*)[72])a_lds, cw_e, cw_r, cdst,
                              INTERX, HID, (long)INTERX * HID, (long)INTERX * HID,
                              cid & 15, (cid >> 4) & 63, (long)(cid >> 10));
            return;
        }
        bid = chunk * 8 + pos;                   // 0..2047
    } else {
        bid = blockIdx.x + gridDim.x * blockIdx.y;
    }

    // swizzle: 16 consecutive by-panels per XCD (L%8), bx outer within XCD
    int L = bid;
    int by = (L & 7) * 16 + ((L >> 3) & 15);
    int bx = L >> 7;

    long e = by >> 3; if (e > 8) e = 8;
    const short* Wb = W + e * sW;
    const float* biasb = (by < 64) ? (bias_e + e * sB) : bias_r;

    int tid = threadIdx.x;
    int lane = tid & 63, wave = tid >> 6;
    int wm = wave & 1, wn = wave >> 1;
    int lm = lane & 15, lq = lane >> 4;
    int lr = lane >> 3, ch = lane & 7;
    int chs = (ch ^ lr) * 8;               // XOR-swizzled global chunk offset

    const short* pA[4];
    const short* pB[8];
#pragma unroll
    for (int it = 0; it < 4; it++) {
        int row = (wave * 4 + it) * 8 + lr;            // 0..127
        if (GATHER) {
            int s = map2[by * 128 + row];
            pA[it] = (s >= 0) ? (A + (long)s * K) : zbuf;
        } else {
            pA[it] = A + ((long)by * 128 + row) * K;
        }
    }
#pragma unroll
    for (int it = 0; it < 8; it++) {
        int row = (wave * 8 + it) * 8 + lr;            // 0..255
        pB[it] = Wb + ((long)bx * 256 + row) * K;
    }

    f32x4 acc[4][8];
#pragma unroll
    for (int i = 0; i < 4; i++)
#pragma unroll
        for (int j = 0; j < 8; j++) acc[i][j] = { 0.f, 0.f, 0.f, 0.f };

    for (int kb = 0; kb < K; kb += 64) {
#pragma unroll
        for (int it = 0; it < 4; it++)
            gl_lds16(pA[it] + kb + chs, a_lds + (wave * 4 + it) * 512);
#pragma unroll
        for (int it = 0; it < 8; it++)
            gl_lds16(pB[it] + kb + chs, b_lds + (wave * 8 + it) * 512);
        __syncthreads();
#pragma unroll
        for (int ks = 0; ks < 64; ks += 32) {
            int po = ((lq ^ (lm & 7)) * 8) ^ ks;
            bf16x8 af[4], bfr[8];
#pragma unroll
            for (int i = 0; i < 4; i++)
                af[i] = *(const bf16x8*)(a_lds + (wm * 64 + i * 16 + lm) * 64 + po);
#pragma unroll
            for (int j = 0; j < 8; j++)
                bfr[j] = *(const bf16x8*)(b_lds + (wn * 128 + j * 16 + lm) * 64 + po);
#pragma unroll
            for (int i = 0; i < 4; i++)
#pragma unroll
                for (int j = 0; j < 8; j++)
                    acc[i][j] = __builtin_amdgcn_mfma_f32_16x16x32_bf16(af[i], bfr[j], acc[i][j], 0, 0, 0);
        }
        __syncthreads();
    }

    // epilogue: C/D layout col=lane&15 (lm), row=lq*4+r
    float bb[8];
#pragma unroll
    for (int j = 0; j < 8; j++)
        bb[j] = biasb[bx * 256 + wn * 128 + j * 16 + lm];

#pragma unroll
    for (int i = 0; i < 4; i++) {
#pragma unroll
        for (int r = 0; r < 4; r++) {
            long row = (long)by * 128 + wm * 64 + i * 16 + lq * 4 + r;
            if (EPI == 1) {
                short* rp = out + row * N + bx * 256 + wn * 128;
#pragma unroll
                for (int h = 0; h < 2; h++) {
                    int b0 = f2bf(gelu_f(acc[i][h*4+0][r] + bb[h*4+0]));
                    int b1 = f2bf(gelu_f(acc[i][h*4+1][r] + bb[h*4+1]));
                    int b2 = f2bf(gelu_f(acc[i][h*4+2][r] + bb[h*4+2]));
                    int b3 = f2bf(gelu_f(acc[i][h*4+3][r] + bb[h*4+3]));
                    int2 pk;
                    pk.x = (b0 & 0xFFFF) | (b1 << 16);
                    pk.y = (b2 & 0xFFFF) | (b3 << 16);
                    *(int2*)(rp + h * 64 + lm * 4) = pk;   // pi(c)=(c&15)*4+(c>>4)
                }
            } else {
#pragma unroll
                for (int j = 0; j < 8; j++) {
                    int col = bx * 256 + wn * 128 + j * 16 + lm;
                    out[row * N + col] = f2bf(acc[i][j][r] + bb[j]);
                }
            }
        }
    }
}

// ---------------------------------------------------------------------------
// GEMM2: 256x256 block, 8 waves (2Mx4N) of 128x64, BK=64, 8-phase schedule
// (round-1 body, harness-verified). Double-buffered 128 KiB LDS, one
// C-quadrant (16 MFMA) + one half-tile stage per phase, raw s_barrier +
// lgkmcnt(0), counted vmcnt(4) at the tile boundary, setprio around MFMA.
// K=4096 -> 64-deep pipeline (the regime where 8-phase pays, m196/m218).
// ---------------------------------------------------------------------------
template<int EPI, int GATHER>
__global__ __launch_bounds__(512, 2) void gemm8_kernel(
    const short* __restrict__ A, const short* __restrict__ W,
    const float* __restrict__ bias_e, const float* __restrict__ bias_r,
    short* __restrict__ out, const int* __restrict__ map2,
    const short* __restrict__ zbuf, int N, int K, long sW, long sB)
{
    __shared__ __align__(16) short lds[65536];   // 2 x (A 16K shorts | B 16K shorts)

    int L = blockIdx.x;
    int by = (L & 7) * 8 + ((L >> 3) & 7);   // M-block of 256 rows (0..63)
    int bx = L >> 6;                          // N-block of 256 cols

    long e = by >> 2; if (e > 8) e = 8;       // expert region: by<32; residual: e=8
    const short* Wb = W + e * sW;
    const float* biasb = (by < 32) ? (bias_e + e * sB) : bias_r;

    int tid = threadIdx.x;
    int lane = tid & 63, wave = tid >> 6;     // 8 waves
    int wm = wave & 1, wn = wave >> 1;        // 2(M) x 4(N) wave grid
    int lm = lane & 15, lq = lane >> 4;
    int lr = lane >> 3, ch = lane & 7;
    int chs = (ch ^ lr) * 8;                  // XOR-swizzled global k-chunk (shorts)

    const short* pA[4];
    const short* pAb = nullptr;
    if (GATHER) {
#pragma unroll
        for (int h = 0; h < 2; h++)
#pragma unroll
            for (int it = 0; it < 2; it++) {
                int rt = h * 128 + (wave * 2 + it) * 8 + lr;
                int s = map2[by * 256 + rt];
                pA[h * 2 + it] = ((s >= 0) ? (A + (long)s * K) : zbuf) + chs;
            }
    } else {
        pAb = A + ((long)by * 256 + wave * 16 + lr) * K + chs;
    }
    const short* pBb = Wb + ((long)bx * 256 + wave * 16 + lr) * K + chs;

#define A_SRC(h,it,t) (GATHER ? (pA[(h)*2+(it)] + (t)*64) \
                              : (pAb + ((h)*128 + (it)*8)*(long)K + (t)*64))
#define B_SRC(h,it,t) (pBb + ((h)*128 + (it)*8)*(long)K + (t)*64)
#define STAGE_A(b,h,t) do { \
    gl_lds16(A_SRC(h,0,t), lds + (b)*32768 + (h)*8192 + wave*1024); \
    gl_lds16(A_SRC(h,1,t), lds + (b)*32768 + (h)*8192 + wave*1024 + 512); } while (0)
#define STAGE_B(b,h,t) do { \
    gl_lds16(B_SRC(h,0,t), lds + (b)*32768 + 16384 + (h)*8192 + wave*1024); \
    gl_lds16(B_SRC(h,1,t), lds + (b)*32768 + 16384 + (h)*8192 + wave*1024 + 512); } while (0)
#define LOAD_A(QM) do { _Pragma("unroll") \
    for (int i2 = 0; i2 < 4; i2++) { \
        const short* ap = base + (QM)*8192 + wm*4096 + i2*1024 + lm*64; \
        af[i2][0] = *(const bf16x8*)(ap + po0); \
        af[i2][1] = *(const bf16x8*)(ap + po1); } } while (0)
#define LOAD_B(QN,DST) do { _Pragma("unroll") \
    for (int j2 = 0; j2 < 2; j2++) { \
        const short* bp = base + 16384 + (QN)*8192 + wn*2048 + j2*1024 + lm*64; \
        DST[j2][0] = *(const bf16x8*)(bp + po0); \
        DST[j2][1] = *(const bf16x8*)(bp + po1); } } while (0)
#define MFMA_Q(QM,QN,BSRC) do { _Pragma("unroll") \
    for (int i2 = 0; i2 < 4; i2++) { _Pragma("unroll") \
    for (int j2 = 0; j2 < 2; j2++) { \
        f32x4 t0 = acc[(QM)*4+i2][(QN)*2+j2]; \
        t0 = __builtin_amdgcn_mfma_f32_16x16x32_bf16(af[i2][0], BSRC[j2][0], t0, 0, 0, 0); \
        t0 = __builtin_amdgcn_mfma_f32_16x16x32_bf16(af[i2][1], BSRC[j2][1], t0, 0, 0, 0); \
        acc[(QM)*4+i2][(QN)*2+j2] = t0; } } } while (0)
#define SYNC_IN do { \
    __builtin_amdgcn_sched_barrier(0); \
    __builtin_amdgcn_s_barrier(); \
    asm volatile("s_waitcnt lgkmcnt(0)" ::: "memory"); \
    __builtin_amdgcn_sched_barrier(0); \
    __builtin_amdgcn_s_setprio(1); } while (0)
#define SYNC_OUT do { \
    __builtin_amdgcn_s_setprio(0); \
    __builtin_amdgcn_sched_barrier(0); \
    __builtin_amdgcn_s_barrier(); \
    __builtin_amdgcn_sched_barrier(0); } while (0)

    int po0 = (lq ^ (lm & 7)) * 8;
    int po1 = po0 ^ 32;

    f32x4 acc[8][4];
#pragma unroll
    for (int i = 0; i < 8; i++)
#pragma unroll
        for (int j = 0; j < 4; j++) acc[i][j] = { 0.f, 0.f, 0.f, 0.f };

    const int NT = K >> 6;

    // prologue: tile0 fully + A0,B0 of tile1; vmcnt(4) = tile0 landed
    STAGE_A(0, 0, 0); STAGE_B(0, 0, 0);
    STAGE_A(0, 1, 0); STAGE_B(0, 1, 0);
    STAGE_A(1, 0, 1); STAGE_B(1, 0, 1);
    __builtin_amdgcn_sched_barrier(0);
    asm volatile("s_waitcnt vmcnt(4)" ::: "memory");
    __builtin_amdgcn_s_barrier();
    __builtin_amdgcn_sched_barrier(0);

    bf16x8 af[4][2], b0v[2][2], b1v[2][2];

    for (int tt = 0; tt < NT; ++tt) {
        const int cur = tt & 1, nxt = cur ^ 1;
        const bool s1 = (tt + 1 < NT), s2 = (tt + 2 < NT);
        const short* base = lds + cur * 32768;

        // phase 0: quad (0,0)
        LOAD_A(0); LOAD_B(0, b0v);
        if (s1) STAGE_A(nxt, 1, tt + 1);
        SYNC_IN;  MFMA_Q(0, 0, b0v);  SYNC_OUT;

        // phase 1: quad (0,1)
        LOAD_B(1, b1v);
        if (s1) STAGE_B(nxt, 1, tt + 1);
        SYNC_IN;  MFMA_Q(0, 1, b1v);  SYNC_OUT;

        // phase 2: quad (1,0)
        LOAD_A(1);
        if (s2) STAGE_A(cur, 0, tt + 2);
        SYNC_IN;  MFMA_Q(1, 0, b0v);  SYNC_OUT;

        // phase 3: quad (1,1) + tile-boundary counted vmcnt
        if (s2) STAGE_B(cur, 0, tt + 2);
        SYNC_IN;  MFMA_Q(1, 1, b1v);
        __builtin_amdgcn_s_setprio(0);
        __builtin_amdgcn_sched_barrier(0);
        if (s2)      { asm volatile("s_waitcnt vmcnt(4)" ::: "memory"); }
        else if (s1) { asm volatile("s_waitcnt vmcnt(0)" ::: "memory"); }
        __builtin_amdgcn_s_barrier();
        __builtin_amdgcn_sched_barrier(0);
    }

#undef A_SRC
#undef B_SRC
#undef STAGE_A
#undef STAGE_B
#undef LOAD_A
#undef LOAD_B
#undef MFMA_Q
#undef SYNC_IN
#undef SYNC_OUT

    // epilogue: C/D layout col=lm, row=lq*4+r
    float bb[4];
#pragma unroll
    for (int j = 0; j < 4; j++)
        bb[j] = biasb[bx * 256 + (j >> 1) * 128 + wn * 32 + (j & 1) * 16 + lm];

#pragma unroll
    for (int i = 0; i < 8; i++) {
        long rowb = (long)by * 256 + (i >> 2) * 128 + wm * 64 + (i & 3) * 16 + lq * 4;
#pragma unroll
        for (int r = 0; r < 4; r++) {
            long row = rowb + r;
            if (EPI == 1) {
                short* rp = out + row * N + bx * 256;
#pragma unroll
                for (int jj = 0; jj < 2; jj++) {
                    int b0 = f2bf(gelu_f(acc[i][jj * 2 + 0][r] + bb[jj * 2 + 0]));
                    int b1 = f2bf(gelu_f(acc[i][jj * 2 + 1][r] + bb[jj * 2 + 1]));
                    int pk = (b0 & 0xFFFF) | (b1 << 16);
                    *(int*)(rp + (jj * 2 + (wn >> 1)) * 64 + lm * 4 + (wn & 1) * 2) = pk;
                }
            } else {
#pragma unroll
                for (int j = 0; j < 4; j++) {
                    int col = bx * 256 + (j >> 1) * 128 + wn * 32 + (j & 1) * 16 + lm;
                    out[row * N + col] = f2bf(acc[i][j][r] + bb[j]);
                }
            }
        }
    }
}

// ---------------------------------------------------------------------------
// Final combine: out = res_mlp*c0 + gate*expert_out*c1 + residual  (eout bf16)
// ---------------------------------------------------------------------------
__global__ __launch_bounds__(256) void final_kernel(
    const float* __restrict__ x, const short* __restrict__ eout2,
    const int* __restrict__ eidx, const int* __restrict__ slot,
    const float* __restrict__ gate, const float* __restrict__ coef0,
    const float* __restrict__ coef1, float* __restrict__ out)
{
    int s = blockIdx.x, tid = threadIdx.x;
    float c0 = coef0[s], g = gate[s] * coef1[s];
    int sl = slot[s], e = eidx[s];
    float4 xv = *(const float4*)(x + (size_t)s * HID + tid * 4);
    int2 rm = *(const int2*)(eout2 + ((size_t)(NEXP * CAPX + s)) * HID + tid * 4);
    int2 mo = { 0, 0 };
    if (sl >= 0) mo = *(const int2*)(eout2 + ((size_t)(e * CAPX + sl)) * HID + tid * 4);
    float4 o;
    o.x = bflo(rm.x) * c0 + g * bflo(mo.x) + xv.x;
    o.y = bfhi(rm.x) * c0 + g * bfhi(mo.x) + xv.y;
    o.z = bflo(rm.y) * c0 + g * bflo(mo.y) + xv.z;
    o.w = bfhi(rm.y) * c0 + g * bfhi(mo.y) + xv.w;
    *(float4*)(out + (size_t)s * HID + tid * 4) = o;
}

extern "C" void kernel_launch(void* const* d_in, const int* in_sizes, int n_in,
                              void* d_out, int out_size, void* d_ws, size_t ws_size,
                              hipStream_t stream) {
    const float* x           = (const float*)d_in[0];
    const float* attn_nw     = (const float*)d_in[1];
    const float* attn_nb     = (const float*)d_in[2];
    const float* wg          = (const float*)d_in[3];
    const float* inter_w     = (const float*)d_in[4];
    const float* inter_b     = (const float*)d_in[5];
    const float* output_w    = (const float*)d_in[6];
    const float* output_b    = (const float*)d_in[7];
    const float* res_inter_w = (const float*)d_in[8];
    const float* res_inter_b = (const float*)d_in[9];
    const float* res_output_w= (const float*)d_in[10];
    const float* res_output_b= (const float*)d_in[11];
    const float* res_coef    = (const float*)d_in[12];
    float* out = (float*)d_out;

    char* ws = (char*)d_ws;
    size_t off = 0;
    auto alloc = [&](size_t bytes) { void* p = ws + off; off += (bytes + 255) & ~(size_t)255; return p; };
    // region1: attn_bf (16 MiB, dies after GEMM1) then eout2 (32 MiB, GEMM2 out)
    char* region1 = (char*)alloc((size_t)MTOT * HID * 2);               // 32 MiB
    // wreg: w1t [9][4096][1024] bf16 (GEMM1 weights)
    short* wreg   = (short*)alloc((size_t)9 * HID * INTERX * 2);        // 72 MiB
    short* hbuf2  = (short*)alloc((size_t)MTOT * INTERX * 2);           // 128 MiB
    int*   eidx   = (int*)alloc(S_TOK * 4);
    int*   slot   = (int*)alloc(S_TOK * 4);
    float* gate   = (float*)alloc(S_TOK * 4);
    float* c0     = (float*)alloc(S_TOK * 4);
    float* c1     = (float*)alloc(S_TOK * 4);
    int*   map2   = (int*)alloc(MTOT * 4);
    short* zbuf   = (short*)alloc(1024 * 2);

    // w2t: separate 72 MiB if the workspace allows -> convtrans<1> can overlap
    // GEMM1 (interleaved into its grid). Otherwise alias wreg (serial path).
    size_t off_base = off;
    short* w2t_sep = (short*)alloc((size_t)9 * HID * INTERX * 2);       // +72 MiB
    bool sep = (off <= ws_size);
    short* w2t = sep ? w2t_sep : wreg;
    if (!sep) off = off_base;

    short* attn_bf = (short*)region1;
    short* eout2   = (short*)region1;
    short* w1t = wreg;

    // fused: weights for GEMM1 (z<9) + layernorm/gate (z>=9)
    fused_pre_kernel<<<dim3(64, 16, 17), 256, 0, stream>>>(
        inter_w, res_inter_w, w1t,
        x, attn_nw, attn_nb, wg, res_coef,
        attn_bf, eidx, gate, c0, c1, map2, (int*)zbuf);

    assign_kernel<<<1, 256, 0, stream>>>(eidx, slot, map2);

    const int NG1 = (MTOT / 128) * (INTERX / 256);   // 2048 GEMM1 blocks

    if (sep) {
        // merged GEMM1 + interleaved convtrans<1> (period 44 = 8 gemm + 36 conv)
        gemm_kernel<1, 1, 1><<<dim3(NG1 + 9216), 256, 0, stream>>>(
            attn_bf, w1t, inter_b, res_inter_b, hbuf2, map2, zbuf,
            INTERX, HID, (long)HID*INTERX, INTERX,
            output_w, res_output_w, w2t);
    } else {
        gemm_kernel<1, 1, 0><<<dim3(NG1), 256, 0, stream>>>(
            attn_bf, w1t, inter_b, res_inter_b, hbuf2, map2, zbuf,
            INTERX, HID, (long)HID*INTERX, INTERX,
            nullptr, nullptr, nullptr);
        // weights for GEMM2: [9][N=1024][K=4096] bf16, pi-permuted K
        convtrans_kernel<1><<<dim3(HID/64, INTERX/64, 9), 256, 0, stream>>>(
            output_w, res_output_w, w2t, INTERX, HID,
            (long)INTERX*HID, (long)INTERX*HID);
    }

    // merged GEMM2: [16384,4096]@[9-sel][4096->1024] -> eout2 bf16 (plain
    // layout), 8-phase 256^2 body (round-1 verified), 64-deep K pipeline.
    gemm8_kernel<0, 0><<<dim3((MTOT/256) * (HID/256)), 512, 0, stream>>>(
        hbuf2, w2t, output_b, res_output_b, eout2, nullptr, zbuf,
        HID, INTERX, (long)INTERX*HID, HID);

    final_kernel<<<S_TOK, 256, 0, stream>>>(x, eout2, eidx, slot, gate, c0, c1, out);

    (void)in_sizes; (void)n_in; (void)out_size;
}

// Round 8
// 703.551 us; speedup vs baseline: 1.0400x; 1.0050x over previous
//
#include <hip/hip_runtime.h>
#include <hip/hip_bf16.h>
#include <type_traits>

#define S_TOK 8192
#define HID 1024
#define INTERX 4096
#define NEXP 8
#define CAPX 1024
#define MTOT 16384   // merged M: 8192 expert slots + 8192 tokens

using f32x4 = __attribute__((ext_vector_type(4))) float;
using i32x4 = __attribute__((ext_vector_type(4))) int;
using bf16x8 = __attribute__((ext_vector_type(8))) short;

__device__ __forceinline__ short f2bf(float f) {
    union { float f; unsigned u; } v; v.f = f;
    unsigned r = (v.u + 0x7FFFu + ((v.u >> 16) & 1u)) >> 16;
    return (short)r;
}
__device__ __forceinline__ float bflo(int p) {
    union { unsigned u; float f; } v; v.u = (unsigned)p << 16; return v.f;
}
__device__ __forceinline__ float bfhi(int p) {
    union { unsigned u; float f; } v; v.u = (unsigned)p & 0xffff0000u; return v.f;
}

// gelu(x) = x / (1 + e^{-2u}), u = 0.79788456(x + 0.044715x^3)
__device__ __forceinline__ float gelu_f(float x) {
    float x2 = x * x;
    float t = __expf(x * fmaf(x2, -0.07135677f, -1.5957691f));
    return x * __builtin_amdgcn_rcpf(1.0f + t);
}

__device__ __forceinline__ void gl_lds16(const short* g, short* l) {
    __builtin_amdgcn_global_load_lds(
        (const __attribute__((address_space(1))) void*)g,
        (__attribute__((address_space(3))) void*)l, 16, 0, 0);
}

// ---------------------------------------------------------------------------
// Transpose-convert body, 9-way batch: z<8 -> src_e + z*sSrc, z==8 -> src_r.
// src [K][N] fp32 -> dst[z] [N][K] bf16. PERM: apply pi within 64-k groups,
// pi(kl) = (kl&15)*4 + (kl>>4)  (must match GEMM1's packed-store layout).
// NT: non-temporal loads/stores (streaming, no reuse) -- used when fused into
// the GEMM1 grid so conv traffic doesn't evict GEMM's hot L2 B-panels
// (round-6 counter evidence: interleave w/o nt blew FETCH 190->405 MB).
// NOTE: __builtin_nontemporal_* requires ext_vector_type pointers, not
// HIP_vector_type (float4/int4) -- round-7 compile lesson.
// ---------------------------------------------------------------------------
template<int PERM, int NT>
__device__ __forceinline__ void convtrans_body(
    short (*tile)[72],
    const float* __restrict__ src_e, const float* __restrict__ src_r,
    short* __restrict__ dst, int K, int N, long sSrc, long sDst,
    int bxi, int byi, long z)
{
    const float* s = (z < 8) ? (src_e + z * sSrc) : src_r;
    short* d = dst + z * sDst;
    int n0 = bxi * 64, k0 = byi * 64;
    int t = threadIdx.x;
    int br = t >> 4, bc = t & 15;
    const float* sp = s + (long)(k0 + br * 4) * N + n0 + bc * 4;
    float4 r0, r1, r2, r3;
    if (NT) {
        f32x4 n0v = __builtin_nontemporal_load((const f32x4*)(sp));
        f32x4 n1v = __builtin_nontemporal_load((const f32x4*)(sp + N));
        f32x4 n2v = __builtin_nontemporal_load((const f32x4*)(sp + 2 * (long)N));
        f32x4 n3v = __builtin_nontemporal_load((const f32x4*)(sp + 3 * (long)N));
        r0 = { n0v[0], n0v[1], n0v[2], n0v[3] };
        r1 = { n1v[0], n1v[1], n1v[2], n1v[3] };
        r2 = { n2v[0], n2v[1], n2v[2], n2v[3] };
        r3 = { n3v[0], n3v[1], n3v[2], n3v[3] };
    } else {
        r0 = *(const float4*)(sp);
        r1 = *(const float4*)(sp + N);
        r2 = *(const float4*)(sp + 2 * (long)N);
        r3 = *(const float4*)(sp + 3 * (long)N);
    }
    if (PERM) {
        float rr[4][4] = { {r0.x,r0.y,r0.z,r0.w}, {r1.x,r1.y,r1.z,r1.w},
                           {r2.x,r2.y,r2.z,r2.w}, {r3.x,r3.y,r3.z,r3.w} };
#pragma unroll
        for (int j = 0; j < 4; j++) {
            int kl = br * 4 + j;
            int kp = (kl & 15) * 4 + (kl >> 4);
#pragma unroll
            for (int q = 0; q < 4; q++)
                tile[bc * 4 + q][kp] = f2bf(rr[j][q]);
        }
    } else {
        short4 c0 = { f2bf(r0.x), f2bf(r1.x), f2bf(r2.x), f2bf(r3.x) };
        short4 c1 = { f2bf(r0.y), f2bf(r1.y), f2bf(r2.y), f2bf(r3.y) };
        short4 c2 = { f2bf(r0.z), f2bf(r1.z), f2bf(r2.z), f2bf(r3.z) };
        short4 c3 = { f2bf(r0.w), f2bf(r1.w), f2bf(r2.w), f2bf(r3.w) };
        *(short4*)&tile[bc * 4 + 0][br * 4] = c0;
        *(short4*)&tile[bc * 4 + 1][br * 4] = c1;
        *(short4*)&tile[bc * 4 + 2][br * 4] = c2;
        *(short4*)&tile[bc * 4 + 3][br * 4] = c3;
    }
    __syncthreads();
    int n = t >> 2, kc = (t & 3) * 16;
    int4 o0 = *(const int4*)&tile[n][kc];
    int4 o1 = *(const int4*)&tile[n][kc + 8];
    short* dp = d + (long)(n0 + n) * K + k0 + kc;
    if (NT) {
        i32x4 s0 = { o0.x, o0.y, o0.z, o0.w };
        i32x4 s1 = { o1.x, o1.y, o1.z, o1.w };
        __builtin_nontemporal_store(s0, (i32x4*)(dp));
        __builtin_nontemporal_store(s1, (i32x4*)(dp + 8));
    } else {
        *(int4*)(dp) = o0;
        *(int4*)(dp + 8) = o1;
    }
}

template<int PERM>
__global__ __launch_bounds__(256) void convtrans_kernel(
    const float* __restrict__ src_e, const float* __restrict__ src_r,
    short* __restrict__ dst, int K, int N, long sSrc, long sDst)
{
    __shared__ __align__(16) short tile[64][72];
    convtrans_body<PERM, 0>(tile, src_e, src_r, dst, K, N, sSrc, sDst,
                            blockIdx.x, blockIdx.y, (long)blockIdx.z);
}

// ---------------------------------------------------------------------------
// Fused pre-pass: blockIdx.z < 9  -> convtrans<0> (weights for GEMM1)
//                 blockIdx.z >= 9 -> LayerNorm + gate logits + coef logits
// Grid dim3(64, 16, 17), 256 threads.
// ---------------------------------------------------------------------------
__global__ __launch_bounds__(256) void fused_pre_kernel(
    const float* __restrict__ src_e, const float* __restrict__ src_r,
    short* __restrict__ w1t,
    const float* __restrict__ x, const float* __restrict__ nw, const float* __restrict__ nb,
    const float* __restrict__ wg, const float* __restrict__ rcf,
    short* __restrict__ attn_bf, int* __restrict__ eidx, float* __restrict__ gate,
    float* __restrict__ coef0, float* __restrict__ coef1,
    int* __restrict__ map2, int* __restrict__ zbufi)
{
    __shared__ __align__(16) short tile[64][72];   // 9 KiB, aliased by LN branch
    int z = blockIdx.z;
    if (z < 9) {
        convtrans_body<0, 0>(tile, src_e, src_r, w1t, HID, INTERX,
                             (long)HID * INTERX, (long)HID * INTERX,
                             blockIdx.x, blockIdx.y, (long)z);
        return;
    }
    // ---- LayerNorm + gate branch ----
    int s = (z - 9) * 1024 + blockIdx.y * 64 + blockIdx.x;   // 0..8191
    int tid = threadIdx.x;
    int lane = tid & 63, wave = tid >> 6;
    double (*gred)[10] = (double(*)[10])(&tile[0][0]);       // 320 B
    float  (*wred)[2]  = (float(*)[2])(&tile[32][0]);        // offset 4608 B

    if (tid == 0) {
        map2[s] = -1;                 // expert-slot region default
        map2[NEXP * CAPX + s] = s;    // residual region identity
    }
    if (s == 0) ((int2*)zbufi)[tid] = int2{0, 0};

    float4 xv = *(const float4*)(x + (size_t)s * HID + tid * 4);
    float sum = xv.x + xv.y + xv.z + xv.w;
    float sq  = xv.x*xv.x + xv.y*xv.y + xv.z*xv.z + xv.w*xv.w;
#pragma unroll
    for (int o = 32; o > 0; o >>= 1) {
        sum += __shfl_down(sum, o, 64);
        sq  += __shfl_down(sq, o, 64);
    }
    if (lane == 0) { wred[wave][0] = sum; wred[wave][1] = sq; }
    __syncthreads();
    float ts = wred[0][0] + wred[1][0] + wred[2][0] + wred[3][0];
    float tq = wred[0][1] + wred[1][1] + wred[2][1] + wred[3][1];
    float m  = ts * (1.0f / HID);
    float var = tq * (1.0f / HID) - m * m;
    float rs = rsqrtf(var + 1e-12f);

    float4 g4 = *(const float4*)(nw + tid * 4);
    float4 b4 = *(const float4*)(nb + tid * 4);
    float y[4];
    y[0] = (xv.x - m) * rs * g4.x + b4.x;
    y[1] = (xv.y - m) * rs * g4.y + b4.y;
    y[2] = (xv.z - m) * rs * g4.z + b4.z;
    y[3] = (xv.w - m) * rs * g4.w + b4.w;

    short4 yb = { f2bf(y[0]), f2bf(y[1]), f2bf(y[2]), f2bf(y[3]) };
    *(short4*)(attn_bf + (size_t)s * HID + tid * 4) = yb;

    double a[10];
#pragma unroll
    for (int q = 0; q < 10; q++) a[q] = 0.0;
#pragma unroll
    for (int j = 0; j < 4; j++) {
        int k = tid * 4 + j;
        float4 w0 = *(const float4*)(wg + k * 8);
        float4 w1 = *(const float4*)(wg + k * 8 + 4);
        double yj = (double)y[j];
        a[0] += yj * w0.x; a[1] += yj * w0.y; a[2] += yj * w0.z; a[3] += yj * w0.w;
        a[4] += yj * w1.x; a[5] += yj * w1.y; a[6] += yj * w1.z; a[7] += yj * w1.w;
        float2 rc = *(const float2*)(rcf + k * 2);
        a[8] += yj * rc.x; a[9] += yj * rc.y;
    }
#pragma unroll
    for (int o = 32; o > 0; o >>= 1)
#pragma unroll
        for (int q = 0; q < 10; q++) a[q] += __shfl_down(a[q], o, 64);
    if (lane == 0)
#pragma unroll
        for (int q = 0; q < 10; q++) gred[wave][q] = a[q];
    __syncthreads();
    if (tid == 0) {
        float l[8];
#pragma unroll
        for (int e = 0; e < 8; e++)
            l[e] = (float)(gred[0][e] + gred[1][e] + gred[2][e] + gred[3][e]);
        int bi = 0; float bv = l[0];
#pragma unroll
        for (int e = 1; e < 8; e++) if (l[e] > bv) { bv = l[e]; bi = e; }
        float den = 0.0f;
#pragma unroll
        for (int e = 0; e < 8; e++) den += expf(l[e] - bv);
        gate[s] = 1.0f / den;
        eidx[s] = bi;
        float r0 = (float)(gred[0][8] + gred[1][8] + gred[2][8] + gred[3][8]);
        float r1 = (float)(gred[0][9] + gred[1][9] + gred[2][9] + gred[3][9]);
        float mx = fmaxf(r0, r1);
        float e0 = expf(r0 - mx), e1 = expf(r1 - mx);
        float inv = 1.0f / (e0 + e1);
        coef0[s] = e0 * inv; coef1[s] = e1 * inv;
    }
}

// ---------------------------------------------------------------------------
// Capacity assignment (token-order exclusive cumsum per expert), 1 block.
// eidx staged coalesced into LDS first.
// ---------------------------------------------------------------------------
__global__ __launch_bounds__(256) void assign_kernel(
    const int* __restrict__ eidx, int* __restrict__ slot, int* __restrict__ map2)
{
    int tid = threadIdx.x;
    __shared__ int se[S_TOK];          // 32 KiB
    __shared__ int cnt[2][256][NEXP];  // 16 KiB
#pragma unroll
    for (int i = 0; i < S_TOK / 4 / 256; i++)      // 8 coalesced int4 loads
        ((int4*)se)[tid + i * 256] = ((const int4*)eidx)[tid + i * 256];
    __syncthreads();

    int c[NEXP];
#pragma unroll
    for (int e = 0; e < NEXP; e++) c[e] = 0;
    int base = tid * 32;
#pragma unroll
    for (int q = 0; q < 8; q++) {
        int4 v = ((const int4*)se)[tid * 8 + q];
        c[v.x]++; c[v.y]++; c[v.z]++; c[v.w]++;
    }
#pragma unroll
    for (int e = 0; e < NEXP; e++) cnt[0][tid][e] = c[e];
    __syncthreads();

    int src = 0;
    for (int step = 1; step < 256; step <<= 1) {
        int dst = src ^ 1;
#pragma unroll
        for (int e = 0; e < NEXP; e++) {
            int v = cnt[src][tid][e];
            if (tid >= step) v += cnt[src][tid - step][e];
            cnt[dst][tid][e] = v;
        }
        __syncthreads();
        src = dst;
    }
    int off[NEXP];
#pragma unroll
    for (int e = 0; e < NEXP; e++) off[e] = (tid > 0) ? cnt[src][tid - 1][e] : 0;
    for (int t = 0; t < 32; t++) {
        int s = base + t;
        int e = se[s];
        int loc = off[e]++;
        if (loc < CAPX) { slot[s] = loc; map2[e * CAPX + loc] = s; }
        else            { slot[s] = -1; }
    }
}

// ---------------------------------------------------------------------------
// Merged GEMM1, 128(M)x256(N) block, 4 waves of 64x128, BK=64 (round-0,
// harness-verified structure). global_load_lds staging + XOR chunk swizzle.
// ILV=1: convtrans<1> blocks INTERLEAVED into the grid, period 44 =
//   8 GEMM + 36 conv; conv uses NON-TEMPORAL loads/stores so its streaming
//   traffic doesn't evict GEMM's L2-resident B-panels (round-6 lesson).
// ILV=0: plain GEMM grid (fallback when workspace can't hold separate w2t).
// EPI 1: gelu + pi-packed int2 bf16 stores. EPI 0: bias + bf16, plain.
// ---------------------------------------------------------------------------
template<int EPI, int GATHER, int ILV>
__global__ __launch_bounds__(256, 2) void gemm_kernel(
    const short* __restrict__ A, const short* __restrict__ W,
    const float* __restrict__ bias_e, const float* __restrict__ bias_r,
    short* __restrict__ out, const int* __restrict__ map2,
    const short* __restrict__ zbuf, int N, int K, long sW, long sB,
    const float* __restrict__ cw_e, const float* __restrict__ cw_r,
    short* __restrict__ cdst)
{
    __shared__ __align__(16) short a_lds[128 * 64];
    __shared__ __align__(16) short b_lds[256 * 64];

    int bid;
    if (ILV) {
        int raw = blockIdx.x;
        int chunk = raw / 44, pos = raw - chunk * 44;
        if (pos >= 8) {
            // interleaved convtrans<1>, non-temporal (streaming)
            int cid = chunk * 36 + (pos - 8);    // 0..9215
            convtrans_body<1, 1>((short(*)[72])a_lds, cw_e, cw_r, cdst,
                                 INTERX, HID, (long)INTERX * HID, (long)INTERX * HID,
                                 cid & 15, (cid >> 4) & 63, (long)(cid >> 10));
            return;
        }
        bid = chunk * 8 + pos;                   // 0..2047
    } else {
        bid = blockIdx.x + gridDim.x * blockIdx.y;
    }

    // swizzle: 16 consecutive by-panels per XCD (L%8), bx outer within XCD
    int L = bid;
    int by = (L & 7) * 16 + ((L >> 3) & 15);
    int bx = L >> 7;

    long e = by >> 3; if (e > 8) e = 8;
    const short* Wb = W + e * sW;
    const float* biasb = (by < 64) ? (bias_e + e * sB) : bias_r;

    int tid = threadIdx.x;
    int lane = tid & 63, wave = tid >> 6;
    int wm = wave & 1, wn = wave >> 1;
    int lm = lane & 15, lq = lane >> 4;
    int lr = lane >> 3, ch = lane & 7;
    int chs = (ch ^ lr) * 8;               // XOR-swizzled global chunk offset

    const short* pA[4];
    const short* pB[8];
#pragma unroll
    for (int it = 0; it < 4; it++) {
        int row = (wave * 4 + it) * 8 + lr;            // 0..127
        if (GATHER) {
            int s = map2[by * 128 + row];
            pA[it] = (s >= 0) ? (A + (long)s * K) : zbuf;
        } else {
            pA[it] = A + ((long)by * 128 + row) * K;
        }
    }
#pragma unroll
    for (int it = 0; it < 8; it++) {
        int row = (wave * 8 + it) * 8 + lr;            // 0..255
        pB[it] = Wb + ((long)bx * 256 + row) * K;
    }

    f32x4 acc[4][8];
#pragma unroll
    for (int i = 0; i < 4; i++)
#pragma unroll
        for (int j = 0; j < 8; j++) acc[i][j] = { 0.f, 0.f, 0.f, 0.f };

    for (int kb = 0; kb < K; kb += 64) {
#pragma unroll
        for (int it = 0; it < 4; it++)
            gl_lds16(pA[it] + kb + chs, a_lds + (wave * 4 + it) * 512);
#pragma unroll
        for (int it = 0; it < 8; it++)
            gl_lds16(pB[it] + kb + chs, b_lds + (wave * 8 + it) * 512);
        __syncthreads();
#pragma unroll
        for (int ks = 0; ks < 64; ks += 32) {
            int po = ((lq ^ (lm & 7)) * 8) ^ ks;
            bf16x8 af[4], bfr[8];
#pragma unroll
            for (int i = 0; i < 4; i++)
                af[i] = *(const bf16x8*)(a_lds + (wm * 64 + i * 16 + lm) * 64 + po);
#pragma unroll
            for (int j = 0; j < 8; j++)
                bfr[j] = *(const bf16x8*)(b_lds + (wn * 128 + j * 16 + lm) * 64 + po);
#pragma unroll
            for (int i = 0; i < 4; i++)
#pragma unroll
                for (int j = 0; j < 8; j++)
                    acc[i][j] = __builtin_amdgcn_mfma_f32_16x16x32_bf16(af[i], bfr[j], acc[i][j], 0, 0, 0);
        }
        __syncthreads();
    }

    // epilogue: C/D layout col=lane&15 (lm), row=lq*4+r
    float bb[8];
#pragma unroll
    for (int j = 0; j < 8; j++)
        bb[j] = biasb[bx * 256 + wn * 128 + j * 16 + lm];

#pragma unroll
    for (int i = 0; i < 4; i++) {
#pragma unroll
        for (int r = 0; r < 4; r++) {
            long row = (long)by * 128 + wm * 64 + i * 16 + lq * 4 + r;
            if (EPI == 1) {
                short* rp = out + row * N + bx * 256 + wn * 128;
#pragma unroll
                for (int h = 0; h < 2; h++) {
                    int b0 = f2bf(gelu_f(acc[i][h*4+0][r] + bb[h*4+0]));
                    int b1 = f2bf(gelu_f(acc[i][h*4+1][r] + bb[h*4+1]));
                    int b2 = f2bf(gelu_f(acc[i][h*4+2][r] + bb[h*4+2]));
                    int b3 = f2bf(gelu_f(acc[i][h*4+3][r] + bb[h*4+3]));
                    int2 pk;
                    pk.x = (b0 & 0xFFFF) | (b1 << 16);
                    pk.y = (b2 & 0xFFFF) | (b3 << 16);
                    *(int2*)(rp + h * 64 + lm * 4) = pk;   // pi(c)=(c&15)*4+(c>>4)
                }
            } else {
#pragma unroll
                for (int j = 0; j < 8; j++) {
                    int col = bx * 256 + wn * 128 + j * 16 + lm;
                    out[row * N + col] = f2bf(acc[i][j][r] + bb[j]);
                }
            }
        }
    }
}

// ---------------------------------------------------------------------------
// GEMM2: 256x256 block, 8 waves (2Mx4N) of 128x64, BK=64, 8-phase schedule
// (round-1 body, harness-verified; round-6 evidence: ~20 us faster than the
// 2-barrier body at K=4096 -- the 64-deep pipeline regime where it pays).
// ---------------------------------------------------------------------------
template<int EPI, int GATHER>
__global__ __launch_bounds__(512, 2) void gemm8_kernel(
    const short* __restrict__ A, const short* __restrict__ W,
    const float* __restrict__ bias_e, const float* __restrict__ bias_r,
    short* __restrict__ out, const int* __restrict__ map2,
    const short* __restrict__ zbuf, int N, int K, long sW, long sB)
{
    __shared__ __align__(16) short lds[65536];   // 2 x (A 16K shorts | B 16K shorts)

    int L = blockIdx.x;
    int by = (L & 7) * 8 + ((L >> 3) & 7);   // M-block of 256 rows (0..63)
    int bx = L >> 6;                          // N-block of 256 cols

    long e = by >> 2; if (e > 8) e = 8;       // expert region: by<32; residual: e=8
    const short* Wb = W + e * sW;
    const float* biasb = (by < 32) ? (bias_e + e * sB) : bias_r;

    int tid = threadIdx.x;
    int lane = tid & 63, wave = tid >> 6;     // 8 waves
    int wm = wave & 1, wn = wave >> 1;        // 2(M) x 4(N) wave grid
    int lm = lane & 15, lq = lane >> 4;
    int lr = lane >> 3, ch = lane & 7;
    int chs = (ch ^ lr) * 8;                  // XOR-swizzled global k-chunk (shorts)

    const short* pA[4];
    const short* pAb = nullptr;
    if (GATHER) {
#pragma unroll
        for (int h = 0; h < 2; h++)
#pragma unroll
            for (int it = 0; it < 2; it++) {
                int rt = h * 128 + (wave * 2 + it) * 8 + lr;
                int s = map2[by * 256 + rt];
                pA[h * 2 + it] = ((s >= 0) ? (A + (long)s * K) : zbuf) + chs;
            }
    } else {
        pAb = A + ((long)by * 256 + wave * 16 + lr) * K + chs;
    }
    const short* pBb = Wb + ((long)bx * 256 + wave * 16 + lr) * K + chs;

#define A_SRC(h,it,t) (GATHER ? (pA[(h)*2+(it)] + (t)*64) \
                              : (pAb + ((h)*128 + (it)*8)*(long)K + (t)*64))
#define B_SRC(h,it,t) (pBb + ((h)*128 + (it)*8)*(long)K + (t)*64)
#define STAGE_A(b,h,t) do { \
    gl_lds16(A_SRC(h,0,t), lds + (b)*32768 + (h)*8192 + wave*1024); \
    gl_lds16(A_SRC(h,1,t), lds + (b)*32768 + (h)*8192 + wave*1024 + 512); } while (0)
#define STAGE_B(b,h,t) do { \
    gl_lds16(B_SRC(h,0,t), lds + (b)*32768 + 16384 + (h)*8192 + wave*1024); \
    gl_lds16(B_SRC(h,1,t), lds + (b)*32768 + 16384 + (h)*8192 + wave*1024 + 512); } while (0)
#define LOAD_A(QM) do { _Pragma("unroll") \
    for (int i2 = 0; i2 < 4; i2++) { \
        const short* ap = base + (QM)*8192 + wm*4096 + i2*1024 + lm*64; \
        af[i2][0] = *(const bf16x8*)(ap + po0); \
        af[i2][1] = *(const bf16x8*)(ap + po1); } } while (0)
#define LOAD_B(QN,DST) do { _Pragma("unroll") \
    for (int j2 = 0; j2 < 2; j2++) { \
        const short* bp = base + 16384 + (QN)*8192 + wn*2048 + j2*1024 + lm*64; \
        DST[j2][0] = *(const bf16x8*)(bp + po0); \
        DST[j2][1] = *(const bf16x8*)(bp + po1); } } while (0)
#define MFMA_Q(QM,QN,BSRC) do { _Pragma("unroll") \
    for (int i2 = 0; i2 < 4; i2++) { _Pragma("unroll") \
    for (int j2 = 0; j2 < 2; j2++) { \
        f32x4 t0 = acc[(QM)*4+i2][(QN)*2+j2]; \
        t0 = __builtin_amdgcn_mfma_f32_16x16x32_bf16(af[i2][0], BSRC[j2][0], t0, 0, 0, 0); \
        t0 = __builtin_amdgcn_mfma_f32_16x16x32_bf16(af[i2][1], BSRC[j2][1], t0, 0, 0, 0); \
        acc[(QM)*4+i2][(QN)*2+j2] = t0; } } } while (0)
#define SYNC_IN do { \
    __builtin_amdgcn_sched_barrier(0); \
    __builtin_amdgcn_s_barrier(); \
    asm volatile("s_waitcnt lgkmcnt(0)" ::: "memory"); \
    __builtin_amdgcn_sched_barrier(0); \
    __builtin_amdgcn_s_setprio(1); } while (0)
#define SYNC_OUT do { \
    __builtin_amdgcn_s_setprio(0); \
    __builtin_amdgcn_sched_barrier(0); \
    __builtin_amdgcn_s_barrier(); \
    __builtin_amdgcn_sched_barrier(0); } while (0)

    int po0 = (lq ^ (lm & 7)) * 8;
    int po1 = po0 ^ 32;

    f32x4 acc[8][4];
#pragma unroll
    for (int i = 0; i < 8; i++)
#pragma unroll
        for (int j = 0; j < 4; j++) acc[i][j] = { 0.f, 0.f, 0.f, 0.f };

    const int NT = K >> 6;

    // prologue: tile0 fully + A0,B0 of tile1; vmcnt(4) = tile0 landed
    STAGE_A(0, 0, 0); STAGE_B(0, 0, 0);
    STAGE_A(0, 1, 0); STAGE_B(0, 1, 0);
    STAGE_A(1, 0, 1); STAGE_B(1, 0, 1);
    __builtin_amdgcn_sched_barrier(0);
    asm volatile("s_waitcnt vmcnt(4)" ::: "memory");
    __builtin_amdgcn_s_barrier();
    __builtin_amdgcn_sched_barrier(0);

    bf16x8 af[4][2], b0v[2][2], b1v[2][2];

    for (int tt = 0; tt < NT; ++tt) {
        const int cur = tt & 1, nxt = cur ^ 1;
        const bool s1 = (tt + 1 < NT), s2 = (tt + 2 < NT);
        const short* base = lds + cur * 32768;

        // phase 0: quad (0,0)
        LOAD_A(0); LOAD_B(0, b0v);
        if (s1) STAGE_A(nxt, 1, tt + 1);
        SYNC_IN;  MFMA_Q(0, 0, b0v);  SYNC_OUT;

        // phase 1: quad (0,1)
        LOAD_B(1, b1v);
        if (s1) STAGE_B(nxt, 1, tt + 1);
        SYNC_IN;  MFMA_Q(0, 1, b1v);  SYNC_OUT;

        // phase 2: quad (1,0)
        LOAD_A(1);
        if (s2) STAGE_A(cur, 0, tt + 2);
        SYNC_IN;  MFMA_Q(1, 0, b0v);  SYNC_OUT;

        // phase 3: quad (1,1) + tile-boundary counted vmcnt
        if (s2) STAGE_B(cur, 0, tt + 2);
        SYNC_IN;  MFMA_Q(1, 1, b1v);
        __builtin_amdgcn_s_setprio(0);
        __builtin_amdgcn_sched_barrier(0);
        if (s2)      { asm volatile("s_waitcnt vmcnt(4)" ::: "memory"); }
        else if (s1) { asm volatile("s_waitcnt vmcnt(0)" ::: "memory"); }
        __builtin_amdgcn_s_barrier();
        __builtin_amdgcn_sched_barrier(0);
    }

#undef A_SRC
#undef B_SRC
#undef STAGE_A
#undef STAGE_B
#undef LOAD_A
#undef LOAD_B
#undef MFMA_Q
#undef SYNC_IN
#undef SYNC_OUT

    // epilogue: C/D layout col=lm, row=lq*4+r
    float bb[4];
#pragma unroll
    for (int j = 0; j < 4; j++)
        bb[j] = biasb[bx * 256 + (j >> 1) * 128 + wn * 32 + (j & 1) * 16 + lm];

#pragma unroll
    for (int i = 0; i < 8; i++) {
        long rowb = (long)by * 256 + (i >> 2) * 128 + wm * 64 + (i & 3) * 16 + lq * 4;
#pragma unroll
        for (int r = 0; r < 4; r++) {
            long row = rowb + r;
            if (EPI == 1) {
                short* rp = out + row * N + bx * 256;
#pragma unroll
                for (int jj = 0; jj < 2; jj++) {
                    int b0 = f2bf(gelu_f(acc[i][jj * 2 + 0][r] + bb[jj * 2 + 0]));
                    int b1 = f2bf(gelu_f(acc[i][jj * 2 + 1][r] + bb[jj * 2 + 1]));
                    int pk = (b0 & 0xFFFF) | (b1 << 16);
                    *(int*)(rp + (jj * 2 + (wn >> 1)) * 64 + lm * 4 + (wn & 1) * 2) = pk;
                }
            } else {
#pragma unroll
                for (int j = 0; j < 4; j++) {
                    int col = bx * 256 + (j >> 1) * 128 + wn * 32 + (j & 1) * 16 + lm;
                    out[row * N + col] = f2bf(acc[i][j][r] + bb[j]);
                }
            }
        }
    }
}

// ---------------------------------------------------------------------------
// Final combine: out = res_mlp*c0 + gate*expert_out*c1 + residual  (eout bf16)
// ---------------------------------------------------------------------------
__global__ __launch_bounds__(256) void final_kernel(
    const float* __restrict__ x, const short* __restrict__ eout2,
    const int* __restrict__ eidx, const int* __restrict__ slot,
    const float* __restrict__ gate, const float* __restrict__ coef0,
    const float* __restrict__ coef1, float* __restrict__ out)
{
    int s = blockIdx.x, tid = threadIdx.x;
    float c0 = coef0[s], g = gate[s] * coef1[s];
    int sl = slot[s], e = eidx[s];
    float4 xv = *(const float4*)(x + (size_t)s * HID + tid * 4);
    int2 rm = *(const int2*)(eout2 + ((size_t)(NEXP * CAPX + s)) * HID + tid * 4);
    int2 mo = { 0, 0 };
    if (sl >= 0) mo = *(const int2*)(eout2 + ((size_t)(e * CAPX + sl)) * HID + tid * 4);
    float4 o;
    o.x = bflo(rm.x) * c0 + g * bflo(mo.x) + xv.x;
    o.y = bfhi(rm.x) * c0 + g * bfhi(mo.x) + xv.y;
    o.z = bflo(rm.y) * c0 + g * bflo(mo.y) + xv.z;
    o.w = bfhi(rm.y) * c0 + g * bfhi(mo.y) + xv.w;
    *(float4*)(out + (size_t)s * HID + tid * 4) = o;
}

extern "C" void kernel_launch(void* const* d_in, const int* in_sizes, int n_in,
                              void* d_out, int out_size, void* d_ws, size_t ws_size,
                              hipStream_t stream) {
    const float* x           = (const float*)d_in[0];
    const float* attn_nw     = (const float*)d_in[1];
    const float* attn_nb     = (const float*)d_in[2];
    const float* wg          = (const float*)d_in[3];
    const float* inter_w     = (const float*)d_in[4];
    const float* inter_b     = (const float*)d_in[5];
    const float* output_w    = (const float*)d_in[6];
    const float* output_b    = (const float*)d_in[7];
    const float* res_inter_w = (const float*)d_in[8];
    const float* res_inter_b = (const float*)d_in[9];
    const float* res_output_w= (const float*)d_in[10];
    const float* res_output_b= (const float*)d_in[11];
    const float* res_coef    = (const float*)d_in[12];
    float* out = (float*)d_out;

    char* ws = (char*)d_ws;
    size_t off = 0;
    auto alloc = [&](size_t bytes) { void* p = ws + off; off += (bytes + 255) & ~(size_t)255; return p; };
    // region1: attn_bf (16 MiB, dies after GEMM1) then eout2 (32 MiB, GEMM2 out)
    char* region1 = (char*)alloc((size_t)MTOT * HID * 2);               // 32 MiB
    // wreg: w1t [9][4096][1024] bf16 (GEMM1 weights)
    short* wreg   = (short*)alloc((size_t)9 * HID * INTERX * 2);        // 72 MiB
    short* hbuf2  = (short*)alloc((size_t)MTOT * INTERX * 2);           // 128 MiB
    int*   eidx   = (int*)alloc(S_TOK * 4);
    int*   slot   = (int*)alloc(S_TOK * 4);
    float* gate   = (float*)alloc(S_TOK * 4);
    float* c0     = (float*)alloc(S_TOK * 4);
    float* c1     = (float*)alloc(S_TOK * 4);
    int*   map2   = (int*)alloc(MTOT * 4);
    short* zbuf   = (short*)alloc(1024 * 2);

    // w2t: separate 72 MiB if the workspace allows -> convtrans<1> can overlap
    // GEMM1 (interleaved into its grid). Otherwise alias wreg (serial path).
    size_t off_base = off;
    short* w2t_sep = (short*)alloc((size_t)9 * HID * INTERX * 2);       // +72 MiB
    bool sep = (off <= ws_size);
    short* w2t = sep ? w2t_sep : wreg;
    if (!sep) off = off_base;

    short* attn_bf = (short*)region1;
    short* eout2   = (short*)region1;
    short* w1t = wreg;

    // fused: weights for GEMM1 (z<9) + layernorm/gate (z>=9)
    fused_pre_kernel<<<dim3(64, 16, 17), 256, 0, stream>>>(
        inter_w, res_inter_w, w1t,
        x, attn_nw, attn_nb, wg, res_coef,
        attn_bf, eidx, gate, c0, c1, map2, (int*)zbuf);

    assign_kernel<<<1, 256, 0, stream>>>(eidx, slot, map2);

    const int NG1 = (MTOT / 128) * (INTERX / 256);   // 2048 GEMM1 blocks

    if (sep) {
        // merged GEMM1 + interleaved non-temporal convtrans<1>
        gemm_kernel<1, 1, 1><<<dim3(NG1 + 9216), 256, 0, stream>>>(
            attn_bf, w1t, inter_b, res_inter_b, hbuf2, map2, zbuf,
            INTERX, HID, (long)HID*INTERX, INTERX,
            output_w, res_output_w, w2t);
    } else {
        gemm_kernel<1, 1, 0><<<dim3(NG1), 256, 0, stream>>>(
            attn_bf, w1t, inter_b, res_inter_b, hbuf2, map2, zbuf,
            INTERX, HID, (long)HID*INTERX, INTERX,
            nullptr, nullptr, nullptr);
        // weights for GEMM2: [9][N=1024][K=4096] bf16, pi-permuted K
        convtrans_kernel<1><<<dim3(HID/64, INTERX/64, 9), 256, 0, stream>>>(
            output_w, res_output_w, w2t, INTERX, HID,
            (long)INTERX*HID, (long)INTERX*HID);
    }

    // merged GEMM2: [16384,4096]@[9-sel][4096->1024] -> eout2 bf16 (plain
    // layout), 8-phase 256^2 body (round-1 verified), 64-deep K pipeline.
    gemm8_kernel<0, 0><<<dim3((MTOT/256) * (HID/256)), 512, 0, stream>>>(
        hbuf2, w2t, output_b, res_output_b, eout2, nullptr, zbuf,
        HID, INTERX, (long)INTERX*HID, HID);

    final_kernel<<<S_TOK, 256, 0, stream>>>(x, eout2, eidx, slot, gate, c0, c1, out);

    (void)in_sizes; (void)n_in; (void)out_size;
}